// Round 3
// baseline (189.388 us; speedup 1.0000x reference)
//
#include <hip/hip_runtime.h>
#include <hip/hip_bf16.h>

// Problem constants
// B=8, C=64, H=256, W=256, NH=4, O=16 (HO=64), MX=32, MY=17
#define NROWS 131072            // B*C*H == B*HO*H
#define MY 17
#define MX 32

// ws layout (floats):
//   [0,512) unused (old tab slot)
//   X1:   [512, +4456448)   (reused as Z later)   [row][ky] float2
//   X2:   [4456960, +557056)  [(b*64+c)*32+kx][ky] float2
//   P:    [5014016, +557056)  [(b*64+ho)*32+kx][ky] float2

// ---------------------------------------------------------------------------
// K1 (radix-4, parity-packed, b128 LDS): X1[row][j] = sum_w x[row][w] e^{-2pi i j w/256}
//   w = l + 64k: e^{-2pi i j 64k/256} = (-i)^{jk}
//   j even: y(l) = s02p + sgn*s13p, sgn = (j&2)? -1 : +1   (real)
//   j odd : y(l) = s02m + i*sgn*s13m, sgn = ((j&3)==1)? -1 : +1
// threads 0..134: even modes (15 pairs x 9), 135..254: odd (15 x 8)
// ---------------------------------------------------------------------------
#define K1_ROWS 30

#define K1_STEP_EVEN(ax, bx, ay, by)                                  \
  { float y0 = fmaf(sgn, (bx), (ax));                                 \
    float y1 = fmaf(sgn, (by), (ay));                                 \
    ar0 = fmaf(y0, pc, ar0); ai0 = fmaf(y0, ps, ai0);                 \
    ar1 = fmaf(y1, pc, ar1); ai1 = fmaf(y1, ps, ai1);                 \
    float nps = fmaf(pc, sj, ps * cj);                                \
    pc = fmaf(pc, cj, -(ps * sj)); ps = nps; }

#define K1_STEP_ODD(ax, bx, ay, by)                                   \
  { float ps2 = sgn * ps, pc2 = sgn * pc;                             \
    ar0 = fmaf((ax), pc, ar0); ar0 = fmaf(-(bx), ps2, ar0);           \
    ai0 = fmaf((ax), ps, ai0); ai0 = fmaf((bx), pc2, ai0);            \
    ar1 = fmaf((ay), pc, ar1); ar1 = fmaf(-(by), ps2, ar1);           \
    ai1 = fmaf((ay), ps, ai1); ai1 = fmaf((by), pc2, ai1);            \
    float nps = fmaf(pc, sj, ps * cj);                                \
    pc = fmaf(pc, cj, -(ps * sj)); ps = nps; }

__global__ __launch_bounds__(256) void k1_fw_w4(const float* __restrict__ x,
                                                float2* __restrict__ X1) {
    __shared__ __align__(16) float s_lds[4][K1_ROWS][68];  // 68*4=272B rows: 16B aligned
    int t = threadIdx.x;
    long rb = (long)blockIdx.x * K1_ROWS;

#pragma unroll
    for (int i = 0; i < 8; ++i) {
        int q = i * 256 + t;
        if (q < K1_ROWS * 64) {
            int r = q >> 6;
            int l = q & 63;
            long row = rb + r;
            float x0 = 0.f, x1v = 0.f, x2v = 0.f, x3v = 0.f;
            if (row < NROWS) {
                const float* xr = x + row * 256 + l;
                x0 = xr[0]; x1v = xr[64]; x2v = xr[128]; x3v = xr[192];
            }
            s_lds[0][r][l] = x0 + x2v;
            s_lds[1][r][l] = x0 - x2v;
            s_lds[2][r][l] = x1v + x3v;
            s_lds[3][r][l] = x1v - x3v;
        }
    }
    __syncthreads();
    if (t >= 255) return;

    int j, g, odd;
    if (t < 135) { g = t / 9; int e = t % 9; j = 2 * e; odd = 0; }
    else         { int u = t - 135; g = u / 8; int o = u % 8; j = 2 * o + 1; odd = 1; }
    int r0 = g * 2;
    float sgn = odd ? (((j & 3) == 1) ? -1.f : 1.f) : ((j & 2) ? -1.f : 1.f);
    float cj, sj;
    sincospif((float)j * (1.0f / 128.0f), &sj, &cj);
    sj = -sj;  // step e^{-2pi i j/256}

    const float4* A4 = (const float4*)&s_lds[odd ? 1 : 0][r0][0];
    const float4* B4 = (const float4*)&s_lds[odd ? 3 : 2][r0][0];
    // row-to-row stride = 68 floats = 17 float4

    float pc = 1.f, ps = 0.f;
    float ar0 = 0, ai0 = 0, ar1 = 0, ai1 = 0;

    if (!odd) {
#pragma unroll 4
        for (int l4 = 0; l4 < 16; ++l4) {
            float4 a0 = A4[l4], b0 = B4[l4], a1 = A4[17 + l4], b1 = B4[17 + l4];
            K1_STEP_EVEN(a0.x, b0.x, a1.x, b1.x)
            K1_STEP_EVEN(a0.y, b0.y, a1.y, b1.y)
            K1_STEP_EVEN(a0.z, b0.z, a1.z, b1.z)
            K1_STEP_EVEN(a0.w, b0.w, a1.w, b1.w)
        }
    } else {
#pragma unroll 4
        for (int l4 = 0; l4 < 16; ++l4) {
            float4 a0 = A4[l4], b0 = B4[l4], a1 = A4[17 + l4], b1 = B4[17 + l4];
            K1_STEP_ODD(a0.x, b0.x, a1.x, b1.x)
            K1_STEP_ODD(a0.y, b0.y, a1.y, b1.y)
            K1_STEP_ODD(a0.z, b0.z, a1.z, b1.z)
            K1_STEP_ODD(a0.w, b0.w, a1.w, b1.w)
        }
    }

    long row = rb + r0;
    if (row < NROWS)     X1[row * 17 + j]       = make_float2(ar0, ai0);
    if (row + 1 < NROWS) X1[(row + 1) * 17 + j] = make_float2(ar1, ai1);
}

// ---------------------------------------------------------------------------
// K2: X2[bc][kx][ky] = sum_h X1[bc*256+h][ky] * e^{-2pi i kx h/256}
// ---------------------------------------------------------------------------
__global__ __launch_bounds__(256) void k2_fw_h(const float2* __restrict__ X1,
                                               float2* __restrict__ X2) {
    __shared__ float2 xs[256 * 17];
    int t = threadIdx.x;
    int bc = blockIdx.x;  // 0..511
    long base = (long)bc * 256 * 17;
    for (int i = 0; i < 17; ++i) xs[i * 256 + t] = X1[base + i * 256 + t];
    __syncthreads();

    for (int q = t; q < 544; q += 256) {
        int kx = q / 17, ky = q % 17;
        float cs, ss;
        sincospif((float)kx * (1.0f / 128.0f), &ss, &cs);
        ss = -ss;  // step e^{-2pi i kx/256}
        float pc = 1.f, psn = 0.f;
        float ar = 0.f, ai = 0.f;
        for (int h = 0; h < 256; ++h) {
            float2 v = xs[h * 17 + ky];
            ar += v.x * pc - v.y * psn;
            ai += v.x * psn + v.y * pc;
            float npc = pc * cs - psn * ss;
            psn = pc * ss + psn * cs;
            pc = npc;
        }
        X2[(long)bc * 544 + q] = make_float2(ar, ai);
    }
}

// ---------------------------------------------------------------------------
// K3: P[b, n*16+o, kx, ky] = sum_i X2[b,i,kx,ky] * (wr + i wi)[n,i,o,kx,ky]
// grid 128: kx = bi&31, n = bi>>5; all 8 batches per block (weights read once)
// ---------------------------------------------------------------------------
__global__ __launch_bounds__(256) void k3_mix(const float2* __restrict__ X2,
                                              const float* __restrict__ wr_g,
                                              const float* __restrict__ wi_g,
                                              float2* __restrict__ P) {
    __shared__ float2 xsh[2176];   // [ii][b][ky] = ii*136 + b*17 + ky
    __shared__ float2 wsh[4352];   // [ii][o][ky] = ii*272 + o*17 + ky
    int t = threadIdx.x;
    int bi = blockIdx.x;
    int kx = bi & 31;
    int n = bi >> 5;

    float accr[9], acci[9];
#pragma unroll
    for (int r = 0; r < 9; ++r) { accr[r] = 0.f; acci[r] = 0.f; }

    for (int ic = 0; ic < 4; ++ic) {
        __syncthreads();
        for (int q = t; q < 2176; q += 256) {
            int ii = q / 136;
            int rem = q % 136;
            int b = rem / 17;
            int ky = rem % 17;
            int i = ic * 16 + ii;
            xsh[q] = X2[((long)(b * 64 + i) * 32 + kx) * 17 + ky];
        }
        for (int q = t; q < 4352; q += 256) {
            int ii = q / 272;
            int rem = q % 272;
            int o = rem / 17;
            int ky = rem % 17;
            int i = ic * 16 + ii;
            long widx = ((long)((n * 64 + i) * 16 + o)) * 544 + kx * 17 + ky;
            wsh[q] = make_float2(wr_g[widx], wi_g[widx]);
        }
        __syncthreads();

#pragma unroll
        for (int rep = 0; rep < 9; ++rep) {
            int q = t + rep * 256;
            if (q < 2176) {
                int ky = q % 17;
                int o = (q / 17) & 15;
                int b = q / 272;
                float ar = 0.f, ai = 0.f;
#pragma unroll
                for (int ii = 0; ii < 16; ++ii) {
                    float2 xv = xsh[ii * 136 + b * 17 + ky];
                    float2 wv = wsh[ii * 272 + o * 17 + ky];
                    ar += xv.x * wv.x - xv.y * wv.y;
                    ai += xv.x * wv.y + xv.y * wv.x;
                }
                accr[rep] += ar; acci[rep] += ai;
            }
        }
    }

#pragma unroll
    for (int rep = 0; rep < 9; ++rep) {
        int q = t + rep * 256;
        if (q < 2176) {
            int ky = q % 17;
            int o = (q / 17) & 15;
            int b = q / 272;
            int ch = b * 64 + n * 16 + o;
            P[((long)ch * 32 + kx) * 17 + ky] = make_float2(accr[rep], acci[rep]);
        }
    }
}

// ---------------------------------------------------------------------------
// K4: Z[bho*256+h][ky] = sum_kx P[bho][kx][ky] * e^{+2pi i kx h/256}
// ---------------------------------------------------------------------------
__global__ __launch_bounds__(256) void k4_inv_h(const float2* __restrict__ P,
                                                float2* __restrict__ Z) {
    __shared__ float2 psh[544];
    int t = threadIdx.x;
    int bho = blockIdx.x;  // 0..511
    long base = (long)bho * 544;
    psh[t] = P[base + t];
    psh[t + 256] = P[base + t + 256];
    if (t < 32) psh[t + 512] = P[base + t + 512];
    __syncthreads();

    float ch, sh;
    sincospif((float)t * (1.0f / 128.0f), &sh, &ch);  // step e^{+2pi i h/256}, h=t
    float pc = 1.f, psn = 0.f;
    float ar[17], ai[17];
#pragma unroll
    for (int ky = 0; ky < 17; ++ky) { ar[ky] = 0.f; ai[ky] = 0.f; }

    for (int kx = 0; kx < 32; ++kx) {
#pragma unroll
        for (int ky = 0; ky < 17; ++ky) {
            float2 v = psh[kx * 17 + ky];
            ar[ky] += v.x * pc - v.y * psn;
            ai[ky] += v.x * psn + v.y * pc;
        }
        float npc = pc * ch - psn * sh;
        psn = pc * sh + psn * ch;
        pc = npc;
    }
    long zb = ((long)bho * 256 + t) * 17;
#pragma unroll
    for (int ky = 0; ky < 17; ++ky) Z[zb + ky] = make_float2(ar[ky], ai[ky]);
}

// ---------------------------------------------------------------------------
// K5: out[row][w] = ( Z[row][0].re + 2*sum_{ky=1..16} Re(Z[row][ky] e^{2pi i ky w/256}) )/65536 + bias
// 2 rows per wave; lane computes w, w+64, w+128, w+192 via i^ky sign patterns
// ---------------------------------------------------------------------------
__global__ __launch_bounds__(256) void k5_inv_w(const float2* __restrict__ Z,
                                                const float* __restrict__ bias,
                                                float* __restrict__ out) {
    __shared__ float2 zs[8][17];
    int t = threadIdx.x;
    long rb = (long)blockIdx.x * 8;
    if (t < 136) ((float2*)zs)[t] = Z[rb * 17 + t];
    __syncthreads();

    int wv = t >> 6;
    int lane = t & 63;
    long r0 = rb + wv * 2;
    int c = (int)((r0 >> 8) & 63);  // rows r0,r0+1 share c (8 | 256)
    float bv = bias[c];

    float c0, s0;
    sincospif((float)lane * (1.0f / 128.0f), &s0, &c0);  // step e^{+2pi i lane/256}
    float pc = c0, psn = s0;  // phasor at ky=1
    float a00 = 0, a01 = 0, a02 = 0, a03 = 0;
    float a10 = 0, a11 = 0, a12 = 0, a13 = 0;

#pragma unroll
    for (int ky = 1; ky <= 16; ++ky) {
        float2 z0 = zs[wv * 2][ky];
        float2 z1 = zs[wv * 2 + 1][ky];
        float A0 = z0.x * pc - z0.y * psn;
        float B0 = z0.x * psn + z0.y * pc;
        float A1 = z1.x * pc - z1.y * psn;
        float B1 = z1.x * psn + z1.y * pc;
        a00 += A0; a10 += A1;
        a01 += ((ky & 3) == 0) ? A0 : ((ky & 3) == 1) ? -B0 : ((ky & 3) == 2) ? -A0 : B0;
        a11 += ((ky & 3) == 0) ? A1 : ((ky & 3) == 1) ? -B1 : ((ky & 3) == 2) ? -A1 : B1;
        a02 += (ky & 1) ? -A0 : A0;
        a12 += (ky & 1) ? -A1 : A1;
        a03 += ((ky & 3) == 0) ? A0 : ((ky & 3) == 1) ? B0 : ((ky & 3) == 2) ? -A0 : -B0;
        a13 += ((ky & 3) == 0) ? A1 : ((ky & 3) == 1) ? B1 : ((ky & 3) == 2) ? -A1 : -B1;
        float npc = pc * c0 - psn * s0;
        psn = pc * s0 + psn * c0;
        pc = npc;
    }
    const float inv = 1.0f / 65536.0f;
    const float inv2 = 2.0f / 65536.0f;
    float base0 = zs[wv * 2][0].x * inv + bv;
    float base1 = zs[wv * 2 + 1][0].x * inv + bv;
    long ob0 = r0 * 256;
    long ob1 = (r0 + 1) * 256;
    out[ob0 + lane]       = fmaf(a00, inv2, base0);
    out[ob0 + 64 + lane]  = fmaf(a01, inv2, base0);
    out[ob0 + 128 + lane] = fmaf(a02, inv2, base0);
    out[ob0 + 192 + lane] = fmaf(a03, inv2, base0);
    out[ob1 + lane]       = fmaf(a10, inv2, base1);
    out[ob1 + 64 + lane]  = fmaf(a11, inv2, base1);
    out[ob1 + 128 + lane] = fmaf(a12, inv2, base1);
    out[ob1 + 192 + lane] = fmaf(a13, inv2, base1);
}

extern "C" void kernel_launch(void* const* d_in, const int* in_sizes, int n_in,
                              void* d_out, int out_size, void* d_ws, size_t ws_size,
                              hipStream_t stream) {
    const float* x = (const float*)d_in[0];
    const float* wr = (const float*)d_in[1];
    const float* wi = (const float*)d_in[2];
    const float* bias = (const float*)d_in[3];
    float* out = (float*)d_out;
    float* ws = (float*)d_ws;

    float2* X1 = (float2*)(ws + 512);
    float2* X2 = (float2*)(ws + 4456960);
    float2* P  = (float2*)(ws + 5014016);
    float2* Z  = X1;  // reuse X1's slot

    int k1_grid = (NROWS + K1_ROWS - 1) / K1_ROWS;  // 4370

    hipLaunchKernelGGL(k1_fw_w4, dim3(k1_grid), dim3(256), 0, stream, x, X1);
    hipLaunchKernelGGL(k2_fw_h, dim3(512), dim3(256), 0, stream, X1, X2);
    hipLaunchKernelGGL(k3_mix, dim3(128), dim3(256), 0, stream, X2, wr, wi, P);
    hipLaunchKernelGGL(k4_inv_h, dim3(512), dim3(256), 0, stream, P, Z);
    hipLaunchKernelGGL(k5_inv_w, dim3(16384), dim3(256), 0, stream, Z, bias, out);
}

// Round 5
// 166.060 us; speedup vs baseline: 1.1405x; 1.1405x over previous
//
#include <hip/hip_runtime.h>
#include <hip/hip_bf16.h>

// Problem constants
// B=8, C=64, H=256, W=256, NH=4, O=16 (HO=64), MX=32, MY=17
#define NROWS 131072            // B*C*H == B*HO*H
#define MY 17
#define MX 32

// ws layout (floats):
//   [0,512) unused
//   X1:   [512, +4456448)   (reused as Z later)   [row][ky] float2
//   X2:   [4456960, +557056)  [(b*64+c)*32+kx][ky] float2
//   P:    [5014016, +557056)  [(b*64+ho)*32+kx][ky] float2

// ---------------------------------------------------------------------------
// K1 (radix-4, uniform mapping, b128 LDS reads):
//   X1[row][j] = sum_w x[row][w] e^{-2pi i j w/256}
//   w = l + 64k: e^{-2pi i j 64k/256} = (-i)^{jk}
//   j even: y(l) = s02p + ca*s13p (real),      ca=(j&2)?-1:+1
//   j odd : y(l) = s02m + i*cb*s13m,           cb=((j&3)==1)?-1:+1
// thread t<255: j=t%17, g=t/17, rows 2g,2g+1
// ---------------------------------------------------------------------------
#define K1_ROWS 30

__global__ __launch_bounds__(256) void k1_fw_w4(const float* __restrict__ x,
                                                float2* __restrict__ X1) {
    __shared__ __align__(16) float s_lds[4][K1_ROWS][68];  // 272B rows, 16B-aligned
    int t = threadIdx.x;
    long rb = (long)blockIdx.x * K1_ROWS;

#pragma unroll
    for (int i = 0; i < 8; ++i) {
        int q = i * 256 + t;
        if (q < K1_ROWS * 64) {
            int r = q >> 6;
            int l = q & 63;
            long row = rb + r;
            float x0 = 0.f, x1v = 0.f, x2v = 0.f, x3v = 0.f;
            if (row < NROWS) {
                const float* xr = x + row * 256 + l;
                x0 = xr[0]; x1v = xr[64]; x2v = xr[128]; x3v = xr[192];
            }
            s_lds[0][r][l] = x0 + x2v;
            s_lds[1][r][l] = x0 - x2v;
            s_lds[2][r][l] = x1v + x3v;
            s_lds[3][r][l] = x1v - x3v;
        }
    }
    __syncthreads();
    if (t >= 255) return;

    int j = t % 17;
    int g = t / 17;
    int r0 = g * 2;
    int odd = j & 1;
    float ca = odd ? 0.f : ((j & 2) ? -1.f : 1.f);
    float cb = odd ? (((j & 3) == 1) ? -1.f : 1.f) : 0.f;
    float cj, sj;
    sincospif((float)j * (1.0f / 128.0f), &sj, &cj);
    sj = -sj;  // step e^{-2pi i j/256}

    const float4* A4 = (const float4*)&s_lds[odd ? 1 : 0][r0][0];
    const float4* B4 = (const float4*)&s_lds[odd ? 3 : 2][r0][0];
    // row stride = 68 floats = 17 float4

    float pc = 1.f, ps = 0.f;
    float ar0 = 0, ai0 = 0, ar1 = 0, ai1 = 0;

#define K1_STEP(vAa0, vBb0, vAa1, vBb1)                               \
  { float ta0 = fmaf(ca, (vBb0), (vAa0));                             \
    float tb0 = cb * (vBb0);                                          \
    float ta1 = fmaf(ca, (vBb1), (vAa1));                             \
    float tb1 = cb * (vBb1);                                          \
    ar0 = fmaf(ta0, pc, ar0); ar0 = fmaf(-tb0, ps, ar0);              \
    ai0 = fmaf(ta0, ps, ai0); ai0 = fmaf(tb0, pc, ai0);               \
    ar1 = fmaf(ta1, pc, ar1); ar1 = fmaf(-tb1, ps, ar1);              \
    ai1 = fmaf(ta1, ps, ai1); ai1 = fmaf(tb1, pc, ai1);               \
    float nps = fmaf(pc, sj, ps * cj);                                \
    pc = fmaf(pc, cj, -(ps * sj)); ps = nps; }

#pragma unroll 2
    for (int l4 = 0; l4 < 16; ++l4) {
        float4 va0 = A4[l4], vb0 = B4[l4], va1 = A4[17 + l4], vb1 = B4[17 + l4];
        K1_STEP(va0.x, vb0.x, va1.x, vb1.x)
        K1_STEP(va0.y, vb0.y, va1.y, vb1.y)
        K1_STEP(va0.z, vb0.z, va1.z, vb1.z)
        K1_STEP(va0.w, vb0.w, va1.w, vb1.w)
    }
#undef K1_STEP

    long row = rb + r0;
    if (row < NROWS)     X1[row * 17 + j]       = make_float2(ar0, ai0);
    if (row + 1 < NROWS) X1[(row + 1) * 17 + j] = make_float2(ar1, ai1);
}

// ---------------------------------------------------------------------------
// K2: X2[bc][kx][ky] = sum_h X1[bc*256+h][ky] * e^{-2pi i kx h/256}
// ---------------------------------------------------------------------------
__global__ __launch_bounds__(256) void k2_fw_h(const float2* __restrict__ X1,
                                               float2* __restrict__ X2) {
    __shared__ float2 xs[256 * 17];
    int t = threadIdx.x;
    int bc = blockIdx.x;  // 0..511
    long base = (long)bc * 256 * 17;
    for (int i = 0; i < 17; ++i) xs[i * 256 + t] = X1[base + i * 256 + t];
    __syncthreads();

    for (int q = t; q < 544; q += 256) {
        int kx = q / 17, ky = q % 17;
        float cs, ss;
        sincospif((float)kx * (1.0f / 128.0f), &ss, &cs);
        ss = -ss;  // step e^{-2pi i kx/256}
        float pc = 1.f, psn = 0.f;
        float ar = 0.f, ai = 0.f;
        for (int h = 0; h < 256; ++h) {
            float2 v = xs[h * 17 + ky];
            ar += v.x * pc - v.y * psn;
            ai += v.x * psn + v.y * pc;
            float npc = pc * cs - psn * ss;
            psn = pc * ss + psn * cs;
            pc = npc;
        }
        X2[(long)bc * 544 + q] = make_float2(ar, ai);
    }
}

// ---------------------------------------------------------------------------
// K3: P[b, n*16+o, kx, ky] = sum_i X2[b,i,kx,ky] * (wr + i wi)[n,i,o,kx,ky]
// grid 512: kx = bi&31, bh = (bi>>5)&3 (2 batches each), n = bi>>7  (R1 version)
// ---------------------------------------------------------------------------
__global__ __launch_bounds__(256) void k3_mix(const float2* __restrict__ X2,
                                              const float* __restrict__ wr_g,
                                              const float* __restrict__ wi_g,
                                              float2* __restrict__ P) {
    __shared__ float2 xsh[544];    // [ii][b][ky]
    __shared__ float2 wsh[4352];   // [ii][o][ky]
    int t = threadIdx.x;
    int bi = blockIdx.x;
    int kx = bi & 31;
    int bh = (bi >> 5) & 3;
    int n = bi >> 7;

    float accr0 = 0, acci0 = 0, accr1 = 0, acci1 = 0, accr2 = 0, acci2 = 0;

    for (int ic = 0; ic < 4; ++ic) {
        __syncthreads();
        for (int q = t; q < 544; q += 256) {
            int ii = q / 34;
            int rem = q % 34;
            int b = rem / 17;
            int ky = rem % 17;
            int i = ic * 16 + ii;
            xsh[q] = X2[((long)((bh * 2 + b) * 64 + i) * 32 + kx) * 17 + ky];
        }
        for (int q = t; q < 4352; q += 256) {
            int ii = q / 272;
            int rem = q % 272;
            int o = rem / 17;
            int ky = rem % 17;
            int i = ic * 16 + ii;
            long widx = ((long)((n * 64 + i) * 16 + o)) * 544 + kx * 17 + ky;
            wsh[q] = make_float2(wr_g[widx], wi_g[widx]);
        }
        __syncthreads();

#pragma unroll 3
        for (int rep = 0; rep < 3; ++rep) {
            int q = t + rep * 256;
            if (q < 544) {
                int ky = q % 17;
                int o = (q / 17) & 15;
                int b = q / 272;
                float ar = 0.f, ai = 0.f;
#pragma unroll
                for (int ii = 0; ii < 16; ++ii) {
                    float2 xv = xsh[ii * 34 + b * 17 + ky];
                    float2 wv = wsh[ii * 272 + o * 17 + ky];
                    ar += xv.x * wv.x - xv.y * wv.y;
                    ai += xv.x * wv.y + xv.y * wv.x;
                }
                if (rep == 0) { accr0 += ar; acci0 += ai; }
                else if (rep == 1) { accr1 += ar; acci1 += ai; }
                else { accr2 += ar; acci2 += ai; }
            }
        }
    }

    {
        int q = t;
        int ky = q % 17, o = (q / 17) & 15, b = q / 272;
        int ch = (bh * 2 + b) * 64 + n * 16 + o;
        P[((long)ch * 32 + kx) * 17 + ky] = make_float2(accr0, acci0);
    }
    {
        int q = t + 256;
        int ky = q % 17, o = (q / 17) & 15, b = q / 272;
        int ch = (bh * 2 + b) * 64 + n * 16 + o;
        P[((long)ch * 32 + kx) * 17 + ky] = make_float2(accr1, acci1);
    }
    if (t < 32) {
        int q = t + 512;
        int ky = q % 17, o = (q / 17) & 15, b = q / 272;
        int ch = (bh * 2 + b) * 64 + n * 16 + o;
        P[((long)ch * 32 + kx) * 17 + ky] = make_float2(accr2, acci2);
    }
}

// ---------------------------------------------------------------------------
// K4: Z[bho*256+h][ky] = sum_kx P[bho][kx][ky] * e^{+2pi i kx h/256}
// ---------------------------------------------------------------------------
__global__ __launch_bounds__(256) void k4_inv_h(const float2* __restrict__ P,
                                                float2* __restrict__ Z) {
    __shared__ float2 psh[544];
    int t = threadIdx.x;
    int bho = blockIdx.x;  // 0..511
    long base = (long)bho * 544;
    psh[t] = P[base + t];
    psh[t + 256] = P[base + t + 256];
    if (t < 32) psh[t + 512] = P[base + t + 512];
    __syncthreads();

    float ch, sh;
    sincospif((float)t * (1.0f / 128.0f), &sh, &ch);  // step e^{+2pi i h/256}, h=t
    float pc = 1.f, psn = 0.f;
    float ar[17], ai[17];
#pragma unroll
    for (int ky = 0; ky < 17; ++ky) { ar[ky] = 0.f; ai[ky] = 0.f; }

    for (int kx = 0; kx < 32; ++kx) {
#pragma unroll
        for (int ky = 0; ky < 17; ++ky) {
            float2 v = psh[kx * 17 + ky];
            ar[ky] += v.x * pc - v.y * psn;
            ai[ky] += v.x * psn + v.y * pc;
        }
        float npc = pc * ch - psn * sh;
        psn = pc * sh + psn * ch;
        pc = npc;
    }
    long zb = ((long)bho * 256 + t) * 17;
#pragma unroll
    for (int ky = 0; ky < 17; ++ky) Z[zb + ky] = make_float2(ar[ky], ai[ky]);
}

// ---------------------------------------------------------------------------
// K5: out[row][w] = ( Z[row][0].re + 2*sum_{ky=1..16} Re(Z[row][ky] e^{2pi i ky w/256}) )/65536 + bias
// 2 rows per wave; lane computes w, w+64, w+128, w+192 via i^ky sign patterns
// ---------------------------------------------------------------------------
__global__ __launch_bounds__(256) void k5_inv_w(const float2* __restrict__ Z,
                                                const float* __restrict__ bias,
                                                float* __restrict__ out) {
    __shared__ float2 zs[8][17];
    int t = threadIdx.x;
    long rb = (long)blockIdx.x * 8;
    if (t < 136) ((float2*)zs)[t] = Z[rb * 17 + t];
    __syncthreads();

    int wv = t >> 6;
    int lane = t & 63;
    long r0 = rb + wv * 2;
    int c = (int)((r0 >> 8) & 63);  // rows r0,r0+1 share c (8 | 256)
    float bv = bias[c];

    float c0, s0;
    sincospif((float)lane * (1.0f / 128.0f), &s0, &c0);  // step e^{+2pi i lane/256}
    float pc = c0, psn = s0;  // phasor at ky=1
    float a00 = 0, a01 = 0, a02 = 0, a03 = 0;
    float a10 = 0, a11 = 0, a12 = 0, a13 = 0;

#pragma unroll
    for (int ky = 1; ky <= 16; ++ky) {
        float2 z0 = zs[wv * 2][ky];
        float2 z1 = zs[wv * 2 + 1][ky];
        float A0 = z0.x * pc - z0.y * psn;
        float B0 = z0.x * psn + z0.y * pc;
        float A1 = z1.x * pc - z1.y * psn;
        float B1 = z1.x * psn + z1.y * pc;
        a00 += A0; a10 += A1;
        a01 += ((ky & 3) == 0) ? A0 : ((ky & 3) == 1) ? -B0 : ((ky & 3) == 2) ? -A0 : B0;
        a11 += ((ky & 3) == 0) ? A1 : ((ky & 3) == 1) ? -B1 : ((ky & 3) == 2) ? -A1 : B1;
        a02 += (ky & 1) ? -A0 : A0;
        a12 += (ky & 1) ? -A1 : A1;
        a03 += ((ky & 3) == 0) ? A0 : ((ky & 3) == 1) ? B0 : ((ky & 3) == 2) ? -A0 : -B0;
        a13 += ((ky & 3) == 0) ? A1 : ((ky & 3) == 1) ? B1 : ((ky & 3) == 2) ? -A1 : -B1;
        float npc = pc * c0 - psn * s0;
        psn = pc * s0 + psn * c0;
        pc = npc;
    }
    const float inv = 1.0f / 65536.0f;
    const float inv2 = 2.0f / 65536.0f;
    float base0 = zs[wv * 2][0].x * inv + bv;
    float base1 = zs[wv * 2 + 1][0].x * inv + bv;
    long ob0 = r0 * 256;
    long ob1 = (r0 + 1) * 256;
    out[ob0 + lane]       = fmaf(a00, inv2, base0);
    out[ob0 + 64 + lane]  = fmaf(a01, inv2, base0);
    out[ob0 + 128 + lane] = fmaf(a02, inv2, base0);
    out[ob0 + 192 + lane] = fmaf(a03, inv2, base0);
    out[ob1 + lane]       = fmaf(a10, inv2, base1);
    out[ob1 + 64 + lane]  = fmaf(a11, inv2, base1);
    out[ob1 + 128 + lane] = fmaf(a12, inv2, base1);
    out[ob1 + 192 + lane] = fmaf(a13, inv2, base1);
}

extern "C" void kernel_launch(void* const* d_in, const int* in_sizes, int n_in,
                              void* d_out, int out_size, void* d_ws, size_t ws_size,
                              hipStream_t stream) {
    const float* x = (const float*)d_in[0];
    const float* wr = (const float*)d_in[1];
    const float* wi = (const float*)d_in[2];
    const float* bias = (const float*)d_in[3];
    float* out = (float*)d_out;
    float* ws = (float*)d_ws;

    float2* X1 = (float2*)(ws + 512);
    float2* X2 = (float2*)(ws + 4456960);
    float2* P  = (float2*)(ws + 5014016);
    float2* Z  = X1;  // reuse X1's slot

    int k1_grid = (NROWS + K1_ROWS - 1) / K1_ROWS;  // 4370

    hipLaunchKernelGGL(k1_fw_w4, dim3(k1_grid), dim3(256), 0, stream, x, X1);
    hipLaunchKernelGGL(k2_fw_h, dim3(512), dim3(256), 0, stream, X1, X2);
    hipLaunchKernelGGL(k3_mix, dim3(512), dim3(256), 0, stream, X2, wr, wi, P);
    hipLaunchKernelGGL(k4_inv_h, dim3(512), dim3(256), 0, stream, P, Z);
    hipLaunchKernelGGL(k5_inv_w, dim3(16384), dim3(256), 0, stream, Z, bias, out);
}

// Round 6
// 157.680 us; speedup vs baseline: 1.2011x; 1.0531x over previous
//
#include <hip/hip_runtime.h>
#include <hip/hip_bf16.h>

// Problem constants
// B=8, C=64, H=256, W=256, NH=4, O=16 (HO=64), MX=32, MY=17
#define NROWS 131072            // B*C*H == B*HO*H
#define MY 17
#define MX 32

// ws layout (floats):
//   [0,512) unused
//   X1:   [512, +4456448)   (reused as Z later)   [row][ky] float2
//   X2:   [4456960, +557056)  [(b*64+c)*32+kx][ky] float2
//   P:    [5014016, +557056)  [(b*64+ho)*32+kx][ky] float2

// ---------------------------------------------------------------------------
// K1 (radix-4, uniform mapping, b128 LDS, register-batched staging):
//   X1[row][j] = sum_w x[row][w] e^{-2pi i j w/256}
//   w = l + 64k: e^{-2pi i j 64k/256} = (-i)^{jk}
//   j even: y(l) = s02p + ca*s13p (real),      ca=(j&2)?-1:+1
//   j odd : y(l) = s02m + i*cb*s13m,           cb=((j&3)==1)?-1:+1
// compute thread t<255: j=t%17, g=t/17, rows 2g,2g+1
// ---------------------------------------------------------------------------
#define K1_ROWS 30

__global__ __launch_bounds__(256) void k1_fw_w4(const float* __restrict__ x,
                                                float2* __restrict__ X1) {
    __shared__ __align__(16) float s_lds[4][K1_ROWS][68];  // 272B rows, 16B-aligned
    int t = threadIdx.x;
    long rb = (long)blockIdx.x * K1_ROWS;

    // stage: item = (r, c): r = item>>4 (row), c = item&15 (float4 chunk in quarter)
    // 30 rows * 16 chunks = 480 items; 2 rounds of 256 (clamped loads, guarded writes)
    float4 q0[2], q1[2], q2[2], q3[2];
#pragma unroll
    for (int i = 0; i < 2; ++i) {
        int item = i * 256 + t;
        int it = item < 480 ? item : 479;
        int r = it >> 4, c = it & 15;
        long row = rb + r;
        if (row >= NROWS) row = NROWS - 1;
        const float4* xr = (const float4*)(x + row * 256) + c;
        q0[i] = xr[0];   // w = c*4 + [0..3]
        q1[i] = xr[16];  // w + 64
        q2[i] = xr[32];  // w + 128
        q3[i] = xr[48];  // w + 192
    }
#pragma unroll
    for (int i = 0; i < 2; ++i) {
        int item = i * 256 + t;
        if (item < 480) {
            int r = item >> 4, c = item & 15;
            float4 s02p, s02m, s13p, s13m;
            s02p.x = q0[i].x + q2[i].x; s02p.y = q0[i].y + q2[i].y;
            s02p.z = q0[i].z + q2[i].z; s02p.w = q0[i].w + q2[i].w;
            s02m.x = q0[i].x - q2[i].x; s02m.y = q0[i].y - q2[i].y;
            s02m.z = q0[i].z - q2[i].z; s02m.w = q0[i].w - q2[i].w;
            s13p.x = q1[i].x + q3[i].x; s13p.y = q1[i].y + q3[i].y;
            s13p.z = q1[i].z + q3[i].z; s13p.w = q1[i].w + q3[i].w;
            s13m.x = q1[i].x - q3[i].x; s13m.y = q1[i].y - q3[i].y;
            s13m.z = q1[i].z - q3[i].z; s13m.w = q1[i].w - q3[i].w;
            *(float4*)&s_lds[0][r][c * 4] = s02p;
            *(float4*)&s_lds[1][r][c * 4] = s02m;
            *(float4*)&s_lds[2][r][c * 4] = s13p;
            *(float4*)&s_lds[3][r][c * 4] = s13m;
        }
    }
    __syncthreads();
    if (t >= 255) return;

    int j = t % 17;
    int g = t / 17;
    int r0 = g * 2;
    int odd = j & 1;
    float ca = odd ? 0.f : ((j & 2) ? -1.f : 1.f);
    float cb = odd ? (((j & 3) == 1) ? -1.f : 1.f) : 0.f;
    float cj, sj;
    sincospif((float)j * (1.0f / 128.0f), &sj, &cj);
    sj = -sj;  // step e^{-2pi i j/256}

    const float4* A4 = (const float4*)&s_lds[odd ? 1 : 0][r0][0];
    const float4* B4 = (const float4*)&s_lds[odd ? 3 : 2][r0][0];
    // row stride = 68 floats = 17 float4

    float pc = 1.f, ps = 0.f;
    float ar0 = 0, ai0 = 0, ar1 = 0, ai1 = 0;

#define K1_STEP(vAa0, vBb0, vAa1, vBb1)                               \
  { float ta0 = fmaf(ca, (vBb0), (vAa0));                             \
    float tb0 = cb * (vBb0);                                          \
    float ta1 = fmaf(ca, (vBb1), (vAa1));                             \
    float tb1 = cb * (vBb1);                                          \
    ar0 = fmaf(ta0, pc, ar0); ar0 = fmaf(-tb0, ps, ar0);              \
    ai0 = fmaf(ta0, ps, ai0); ai0 = fmaf(tb0, pc, ai0);               \
    ar1 = fmaf(ta1, pc, ar1); ar1 = fmaf(-tb1, ps, ar1);              \
    ai1 = fmaf(ta1, ps, ai1); ai1 = fmaf(tb1, pc, ai1);               \
    float nps = fmaf(pc, sj, ps * cj);                                \
    pc = fmaf(pc, cj, -(ps * sj)); ps = nps; }

#pragma unroll 2
    for (int l4 = 0; l4 < 16; ++l4) {
        float4 va0 = A4[l4], vb0 = B4[l4], va1 = A4[17 + l4], vb1 = B4[17 + l4];
        K1_STEP(va0.x, vb0.x, va1.x, vb1.x)
        K1_STEP(va0.y, vb0.y, va1.y, vb1.y)
        K1_STEP(va0.z, vb0.z, va1.z, vb1.z)
        K1_STEP(va0.w, vb0.w, va1.w, vb1.w)
    }
#undef K1_STEP

    long row = rb + r0;
    if (row < NROWS)     X1[row * 17 + j]       = make_float2(ar0, ai0);
    if (row + 1 < NROWS) X1[(row + 1) * 17 + j] = make_float2(ar1, ai1);
}

// ---------------------------------------------------------------------------
// K2: X2[bc][kx][ky] = sum_h X1[bc*256+h][ky] * e^{-2pi i kx h/256}
// 576 threads: one (kx,ky) per thread (t<544); register-batched staging
// ---------------------------------------------------------------------------
__global__ __launch_bounds__(576) void k2_fw_h(const float2* __restrict__ X1,
                                               float2* __restrict__ X2) {
    __shared__ float2 xs[4352];  // [h][ky] = h*17+ky
    int t = threadIdx.x;
    int bc = blockIdx.x;  // 0..511
    long base = (long)bc * 4352;

    float2 rg[8];
#pragma unroll
    for (int i = 0; i < 8; ++i) {
        int q = i * 576 + t;
        rg[i] = X1[base + (q < 4352 ? q : 4351)];
    }
#pragma unroll
    for (int i = 0; i < 8; ++i) {
        int q = i * 576 + t;
        if (q < 4352) xs[q] = rg[i];
    }
    __syncthreads();
    if (t >= 544) return;

    int kx = t / 17, ky = t % 17;
    float cs, ss;
    sincospif((float)kx * (1.0f / 128.0f), &ss, &cs);
    ss = -ss;  // step e^{-2pi i kx/256}
    float pc = 1.f, psn = 0.f;
    float ar = 0.f, ai = 0.f;
#pragma unroll 4
    for (int h = 0; h < 256; ++h) {
        float2 v = xs[h * 17 + ky];
        ar += v.x * pc - v.y * psn;
        ai += v.x * psn + v.y * pc;
        float npc = pc * cs - psn * ss;
        psn = pc * ss + psn * cs;
        pc = npc;
    }
    X2[(long)bc * 544 + t] = make_float2(ar, ai);
}

// ---------------------------------------------------------------------------
// K3: P[b, n*16+o, kx, ky] = sum_i X2[b,i,kx,ky] * (wr + i wi)[n,i,o,kx,ky]
// grid 512: kx = bi&31, bh = (bi>>5)&3 (2 batches each), n = bi>>7  (R1 version)
// ---------------------------------------------------------------------------
__global__ __launch_bounds__(256) void k3_mix(const float2* __restrict__ X2,
                                              const float* __restrict__ wr_g,
                                              const float* __restrict__ wi_g,
                                              float2* __restrict__ P) {
    __shared__ float2 xsh[544];    // [ii][b][ky]
    __shared__ float2 wsh[4352];   // [ii][o][ky]
    int t = threadIdx.x;
    int bi = blockIdx.x;
    int kx = bi & 31;
    int bh = (bi >> 5) & 3;
    int n = bi >> 7;

    float accr0 = 0, acci0 = 0, accr1 = 0, acci1 = 0, accr2 = 0, acci2 = 0;

    for (int ic = 0; ic < 4; ++ic) {
        __syncthreads();
        for (int q = t; q < 544; q += 256) {
            int ii = q / 34;
            int rem = q % 34;
            int b = rem / 17;
            int ky = rem % 17;
            int i = ic * 16 + ii;
            xsh[q] = X2[((long)((bh * 2 + b) * 64 + i) * 32 + kx) * 17 + ky];
        }
        for (int q = t; q < 4352; q += 256) {
            int ii = q / 272;
            int rem = q % 272;
            int o = rem / 17;
            int ky = rem % 17;
            int i = ic * 16 + ii;
            long widx = ((long)((n * 64 + i) * 16 + o)) * 544 + kx * 17 + ky;
            wsh[q] = make_float2(wr_g[widx], wi_g[widx]);
        }
        __syncthreads();

#pragma unroll 3
        for (int rep = 0; rep < 3; ++rep) {
            int q = t + rep * 256;
            if (q < 544) {
                int ky = q % 17;
                int o = (q / 17) & 15;
                int b = q / 272;
                float ar = 0.f, ai = 0.f;
#pragma unroll
                for (int ii = 0; ii < 16; ++ii) {
                    float2 xv = xsh[ii * 34 + b * 17 + ky];
                    float2 wv = wsh[ii * 272 + o * 17 + ky];
                    ar += xv.x * wv.x - xv.y * wv.y;
                    ai += xv.x * wv.y + xv.y * wv.x;
                }
                if (rep == 0) { accr0 += ar; acci0 += ai; }
                else if (rep == 1) { accr1 += ar; acci1 += ai; }
                else { accr2 += ar; acci2 += ai; }
            }
        }
    }

    {
        int q = t;
        int ky = q % 17, o = (q / 17) & 15, b = q / 272;
        int ch = (bh * 2 + b) * 64 + n * 16 + o;
        P[((long)ch * 32 + kx) * 17 + ky] = make_float2(accr0, acci0);
    }
    {
        int q = t + 256;
        int ky = q % 17, o = (q / 17) & 15, b = q / 272;
        int ch = (bh * 2 + b) * 64 + n * 16 + o;
        P[((long)ch * 32 + kx) * 17 + ky] = make_float2(accr1, acci1);
    }
    if (t < 32) {
        int q = t + 512;
        int ky = q % 17, o = (q / 17) & 15, b = q / 272;
        int ch = (bh * 2 + b) * 64 + n * 16 + o;
        P[((long)ch * 32 + kx) * 17 + ky] = make_float2(accr2, acci2);
    }
}

// ---------------------------------------------------------------------------
// K4: Z[bho*256+h][ky] = sum_kx P[bho][kx][ky] * e^{+2pi i kx h/256}
// ---------------------------------------------------------------------------
__global__ __launch_bounds__(256) void k4_inv_h(const float2* __restrict__ P,
                                                float2* __restrict__ Z) {
    __shared__ float2 psh[544];
    int t = threadIdx.x;
    int bho = blockIdx.x;  // 0..511
    long base = (long)bho * 544;
    psh[t] = P[base + t];
    psh[t + 256] = P[base + t + 256];
    if (t < 32) psh[t + 512] = P[base + t + 512];
    __syncthreads();

    float ch, sh;
    sincospif((float)t * (1.0f / 128.0f), &sh, &ch);  // step e^{+2pi i h/256}, h=t
    float pc = 1.f, psn = 0.f;
    float ar[17], ai[17];
#pragma unroll
    for (int ky = 0; ky < 17; ++ky) { ar[ky] = 0.f; ai[ky] = 0.f; }

    for (int kx = 0; kx < 32; ++kx) {
#pragma unroll
        for (int ky = 0; ky < 17; ++ky) {
            float2 v = psh[kx * 17 + ky];
            ar[ky] += v.x * pc - v.y * psn;
            ai[ky] += v.x * psn + v.y * pc;
        }
        float npc = pc * ch - psn * sh;
        psn = pc * sh + psn * ch;
        pc = npc;
    }
    long zb = ((long)bho * 256 + t) * 17;
#pragma unroll
    for (int ky = 0; ky < 17; ++ky) Z[zb + ky] = make_float2(ar[ky], ai[ky]);
}

// ---------------------------------------------------------------------------
// K5: out[row][w] = ( Z[row][0].re + 2*sum_{ky=1..16} Re(Z[row][ky] e^{2pi i ky w/256}) )/65536 + bias
// 2 rows per wave; lane computes w, w+64, w+128, w+192 via i^ky sign patterns
// ---------------------------------------------------------------------------
__global__ __launch_bounds__(256) void k5_inv_w(const float2* __restrict__ Z,
                                                const float* __restrict__ bias,
                                                float* __restrict__ out) {
    __shared__ float2 zs[8][17];
    int t = threadIdx.x;
    long rb = (long)blockIdx.x * 8;
    if (t < 136) ((float2*)zs)[t] = Z[rb * 17 + t];
    __syncthreads();

    int wv = t >> 6;
    int lane = t & 63;
    long r0 = rb + wv * 2;
    int c = (int)((r0 >> 8) & 63);  // rows r0,r0+1 share c (8 | 256)
    float bv = bias[c];

    float c0, s0;
    sincospif((float)lane * (1.0f / 128.0f), &s0, &c0);  // step e^{+2pi i lane/256}
    float pc = c0, psn = s0;  // phasor at ky=1
    float a00 = 0, a01 = 0, a02 = 0, a03 = 0;
    float a10 = 0, a11 = 0, a12 = 0, a13 = 0;

#pragma unroll
    for (int ky = 1; ky <= 16; ++ky) {
        float2 z0 = zs[wv * 2][ky];
        float2 z1 = zs[wv * 2 + 1][ky];
        float A0 = z0.x * pc - z0.y * psn;
        float B0 = z0.x * psn + z0.y * pc;
        float A1 = z1.x * pc - z1.y * psn;
        float B1 = z1.x * psn + z1.y * pc;
        a00 += A0; a10 += A1;
        a01 += ((ky & 3) == 0) ? A0 : ((ky & 3) == 1) ? -B0 : ((ky & 3) == 2) ? -A0 : B0;
        a11 += ((ky & 3) == 0) ? A1 : ((ky & 3) == 1) ? -B1 : ((ky & 3) == 2) ? -A1 : B1;
        a02 += (ky & 1) ? -A0 : A0;
        a12 += (ky & 1) ? -A1 : A1;
        a03 += ((ky & 3) == 0) ? A0 : ((ky & 3) == 1) ? B0 : ((ky & 3) == 2) ? -A0 : -B0;
        a13 += ((ky & 3) == 0) ? A1 : ((ky & 3) == 1) ? B1 : ((ky & 3) == 2) ? -A1 : -B1;
        float npc = pc * c0 - psn * s0;
        psn = pc * s0 + psn * c0;
        pc = npc;
    }
    const float inv = 1.0f / 65536.0f;
    const float inv2 = 2.0f / 65536.0f;
    float base0 = zs[wv * 2][0].x * inv + bv;
    float base1 = zs[wv * 2 + 1][0].x * inv + bv;
    long ob0 = r0 * 256;
    long ob1 = (r0 + 1) * 256;
    out[ob0 + lane]       = fmaf(a00, inv2, base0);
    out[ob0 + 64 + lane]  = fmaf(a01, inv2, base0);
    out[ob0 + 128 + lane] = fmaf(a02, inv2, base0);
    out[ob0 + 192 + lane] = fmaf(a03, inv2, base0);
    out[ob1 + lane]       = fmaf(a10, inv2, base1);
    out[ob1 + 64 + lane]  = fmaf(a11, inv2, base1);
    out[ob1 + 128 + lane] = fmaf(a12, inv2, base1);
    out[ob1 + 192 + lane] = fmaf(a13, inv2, base1);
}

extern "C" void kernel_launch(void* const* d_in, const int* in_sizes, int n_in,
                              void* d_out, int out_size, void* d_ws, size_t ws_size,
                              hipStream_t stream) {
    const float* x = (const float*)d_in[0];
    const float* wr = (const float*)d_in[1];
    const float* wi = (const float*)d_in[2];
    const float* bias = (const float*)d_in[3];
    float* out = (float*)d_out;
    float* ws = (float*)d_ws;

    float2* X1 = (float2*)(ws + 512);
    float2* X2 = (float2*)(ws + 4456960);
    float2* P  = (float2*)(ws + 5014016);
    float2* Z  = X1;  // reuse X1's slot

    int k1_grid = (NROWS + K1_ROWS - 1) / K1_ROWS;  // 4370

    hipLaunchKernelGGL(k1_fw_w4, dim3(k1_grid), dim3(256), 0, stream, x, X1);
    hipLaunchKernelGGL(k2_fw_h, dim3(512), dim3(576), 0, stream, X1, X2);
    hipLaunchKernelGGL(k3_mix, dim3(512), dim3(256), 0, stream, X2, wr, wi, P);
    hipLaunchKernelGGL(k4_inv_h, dim3(512), dim3(256), 0, stream, P, Z);
    hipLaunchKernelGGL(k5_inv_w, dim3(16384), dim3(256), 0, stream, Z, bias, out);
}

// Round 7
// 144.718 us; speedup vs baseline: 1.3087x; 1.0896x over previous
//
#include <hip/hip_runtime.h>
#include <hip/hip_bf16.h>

// Problem constants
// B=8, C=64, H=256, W=256, NH=4, O=16 (HO=64), MX=32, MY=17
#define NROWS 131072
#define MY 17
#define MX 32

// ws layout (floats):
//   X2:   [4456960, +557056)  [(b*64+c)*32+kx][ky] float2
//   P:    [5014016, +557056)  [(b*64+ho)*32+kx][ky] float2

// ---------------------------------------------------------------------------
// F1 = K1+K2 fused, one (b,c) plane per block.
//  K1 (radix-4): X1[h][j] = sum_w x[h][w] e^{-2pi i j w/256}  -> LDS xs[h][j]
//  K2: X2[bc][kx][ky] = sum_h xs[h][ky] e^{-2pi i kx h/256}
// 28-row chunks; regload(c+1) issued before compute(c) to hide HBM latency.
// ---------------------------------------------------------------------------
#define K1_ROWS 28
#define NCHUNK 10   // 9*28 = 252 + 4

__global__ __launch_bounds__(256) void f1_fw(const float* __restrict__ x,
                                             float2* __restrict__ X2) {
    __shared__ __align__(16) float s_lds[4][K1_ROWS][68];  // 30464 B
    __shared__ float2 xs[4352];                            // 34816 B  [h*17+ky]
    int t = threadIdx.x;
    int bc = blockIdx.x;  // 0..511
    const float* xp = x + (long)bc * 65536;

    // compute-phase constants (uniform across chunks)
    int j = t % 17;
    int g = t / 17;      // 0..15; active when r0+2 <= nr
    int r0 = g * 2;
    int odd = j & 1;
    float ca = odd ? 0.f : ((j & 2) ? -1.f : 1.f);
    float cb = odd ? (((j & 3) == 1) ? -1.f : 1.f) : 0.f;
    float cj, sj;
    sincospif((float)j * (1.0f / 128.0f), &sj, &cj);
    sj = -sj;  // step e^{-2pi i j/256}
    const float4* A4 = (const float4*)&s_lds[odd ? 1 : 0][0][0] + r0 * 17;
    const float4* B4 = (const float4*)&s_lds[odd ? 3 : 2][0][0] + r0 * 17;

    float4 q0[2], q1[2], q2[2], q3[2];

#define F1_REGLOAD(cc)                                                         \
    {                                                                          \
        int nr_ = ((cc) < 9) ? K1_ROWS : 4;                                    \
        int items_ = nr_ * 16;                                                 \
        _Pragma("unroll")                                                      \
        for (int i = 0; i < 2; ++i) {                                          \
            int item = i * 256 + t;                                            \
            int it = item < items_ ? item : items_ - 1;                        \
            int r = it >> 4, cq = it & 15;                                     \
            const float4* xr =                                                 \
                (const float4*)(xp + ((cc) * K1_ROWS + r) * 256) + cq;         \
            q0[i] = xr[0];                                                     \
            q1[i] = xr[16];                                                    \
            q2[i] = xr[32];                                                    \
            q3[i] = xr[48];                                                    \
        }                                                                      \
    }

    F1_REGLOAD(0)

    for (int c = 0; c < NCHUNK; ++c) {
        int nr = (c < 9) ? K1_ROWS : 4;
        int items = nr * 16;

        // combine (radix-4 along w) + LDS write, from registers
#pragma unroll
        for (int i = 0; i < 2; ++i) {
            int item = i * 256 + t;
            if (item < items) {
                int r = item >> 4, cq = item & 15;
                float4 s02p, s02m, s13p, s13m;
                s02p.x = q0[i].x + q2[i].x; s02p.y = q0[i].y + q2[i].y;
                s02p.z = q0[i].z + q2[i].z; s02p.w = q0[i].w + q2[i].w;
                s02m.x = q0[i].x - q2[i].x; s02m.y = q0[i].y - q2[i].y;
                s02m.z = q0[i].z - q2[i].z; s02m.w = q0[i].w - q2[i].w;
                s13p.x = q1[i].x + q3[i].x; s13p.y = q1[i].y + q3[i].y;
                s13p.z = q1[i].z + q3[i].z; s13p.w = q1[i].w + q3[i].w;
                s13m.x = q1[i].x - q3[i].x; s13m.y = q1[i].y - q3[i].y;
                s13m.z = q1[i].z - q3[i].z; s13m.w = q1[i].w - q3[i].w;
                *(float4*)&s_lds[0][r][cq * 4] = s02p;
                *(float4*)&s_lds[1][r][cq * 4] = s02m;
                *(float4*)&s_lds[2][r][cq * 4] = s13p;
                *(float4*)&s_lds[3][r][cq * 4] = s13m;
            }
        }
        __syncthreads();

        // prefetch next chunk into registers (in flight during compute)
        if (c + 1 < NCHUNK) F1_REGLOAD(c + 1)

        // 17-mode DFT of this chunk (verified K1 inner loop)
        if (r0 + 2 <= nr) {
            float pc = 1.f, ps = 0.f;
            float ar0 = 0, ai0 = 0, ar1 = 0, ai1 = 0;

#define K1_STEP(vAa0, vBb0, vAa1, vBb1)                               \
  { float ta0 = fmaf(ca, (vBb0), (vAa0));                             \
    float tb0 = cb * (vBb0);                                          \
    float ta1 = fmaf(ca, (vBb1), (vAa1));                             \
    float tb1 = cb * (vBb1);                                          \
    ar0 = fmaf(ta0, pc, ar0); ar0 = fmaf(-tb0, ps, ar0);              \
    ai0 = fmaf(ta0, ps, ai0); ai0 = fmaf(tb0, pc, ai0);               \
    ar1 = fmaf(ta1, pc, ar1); ar1 = fmaf(-tb1, ps, ar1);              \
    ai1 = fmaf(ta1, ps, ai1); ai1 = fmaf(tb1, pc, ai1);               \
    float nps = fmaf(pc, sj, ps * cj);                                \
    pc = fmaf(pc, cj, -(ps * sj)); ps = nps; }

#pragma unroll 2
            for (int l4 = 0; l4 < 16; ++l4) {
                float4 va0 = A4[l4], vb0 = B4[l4];
                float4 va1 = A4[17 + l4], vb1 = B4[17 + l4];
                K1_STEP(va0.x, vb0.x, va1.x, vb1.x)
                K1_STEP(va0.y, vb0.y, va1.y, vb1.y)
                K1_STEP(va0.z, vb0.z, va1.z, vb1.z)
                K1_STEP(va0.w, vb0.w, va1.w, vb1.w)
            }
#undef K1_STEP

            int h = c * K1_ROWS + r0;
            xs[h * 17 + j] = make_float2(ar0, ai0);
            xs[(h + 1) * 17 + j] = make_float2(ar1, ai1);
        }
        __syncthreads();
    }

    // K2 phase (verified loop), reading xs from LDS
    for (int q = t; q < 544; q += 256) {
        int kx = q / 17, ky = q % 17;
        float cs, ss;
        sincospif((float)kx * (1.0f / 128.0f), &ss, &cs);
        ss = -ss;  // step e^{-2pi i kx/256}
        float pc = 1.f, psn = 0.f;
        float ar = 0.f, ai = 0.f;
#pragma unroll 4
        for (int h = 0; h < 256; ++h) {
            float2 v = xs[h * 17 + ky];
            ar += v.x * pc - v.y * psn;
            ai += v.x * psn + v.y * pc;
            float npc = pc * cs - psn * ss;
            psn = pc * ss + psn * cs;
            pc = npc;
        }
        X2[(long)bc * 544 + q] = make_float2(ar, ai);
    }
#undef F1_REGLOAD
}

// ---------------------------------------------------------------------------
// K3: P[b, n*16+o, kx, ky] = sum_i X2[b,i,kx,ky] * (wr + i wi)[n,i,o,kx,ky]
// grid 512: kx = bi&31, bh = (bi>>5)&3 (2 batches each), n = bi>>7 (verified)
// ---------------------------------------------------------------------------
__global__ __launch_bounds__(256) void k3_mix(const float2* __restrict__ X2,
                                              const float* __restrict__ wr_g,
                                              const float* __restrict__ wi_g,
                                              float2* __restrict__ P) {
    __shared__ float2 xsh[544];    // [ii][b][ky]
    __shared__ float2 wsh[4352];   // [ii][o][ky]
    int t = threadIdx.x;
    int bi = blockIdx.x;
    int kx = bi & 31;
    int bh = (bi >> 5) & 3;
    int n = bi >> 7;

    float accr0 = 0, acci0 = 0, accr1 = 0, acci1 = 0, accr2 = 0, acci2 = 0;

    for (int ic = 0; ic < 4; ++ic) {
        __syncthreads();
        for (int q = t; q < 544; q += 256) {
            int ii = q / 34;
            int rem = q % 34;
            int b = rem / 17;
            int ky = rem % 17;
            int i = ic * 16 + ii;
            xsh[q] = X2[((long)((bh * 2 + b) * 64 + i) * 32 + kx) * 17 + ky];
        }
        for (int q = t; q < 4352; q += 256) {
            int ii = q / 272;
            int rem = q % 272;
            int o = rem / 17;
            int ky = rem % 17;
            int i = ic * 16 + ii;
            long widx = ((long)((n * 64 + i) * 16 + o)) * 544 + kx * 17 + ky;
            wsh[q] = make_float2(wr_g[widx], wi_g[widx]);
        }
        __syncthreads();

#pragma unroll 3
        for (int rep = 0; rep < 3; ++rep) {
            int q = t + rep * 256;
            if (q < 544) {
                int ky = q % 17;
                int o = (q / 17) & 15;
                int b = q / 272;
                float ar = 0.f, ai = 0.f;
#pragma unroll
                for (int ii = 0; ii < 16; ++ii) {
                    float2 xv = xsh[ii * 34 + b * 17 + ky];
                    float2 wv = wsh[ii * 272 + o * 17 + ky];
                    ar += xv.x * wv.x - xv.y * wv.y;
                    ai += xv.x * wv.y + xv.y * wv.x;
                }
                if (rep == 0) { accr0 += ar; acci0 += ai; }
                else if (rep == 1) { accr1 += ar; acci1 += ai; }
                else { accr2 += ar; acci2 += ai; }
            }
        }
    }

    {
        int q = t;
        int ky = q % 17, o = (q / 17) & 15, b = q / 272;
        int ch = (bh * 2 + b) * 64 + n * 16 + o;
        P[((long)ch * 32 + kx) * 17 + ky] = make_float2(accr0, acci0);
    }
    {
        int q = t + 256;
        int ky = q % 17, o = (q / 17) & 15, b = q / 272;
        int ch = (bh * 2 + b) * 64 + n * 16 + o;
        P[((long)ch * 32 + kx) * 17 + ky] = make_float2(accr1, acci1);
    }
    if (t < 32) {
        int q = t + 512;
        int ky = q % 17, o = (q / 17) & 15, b = q / 272;
        int ch = (bh * 2 + b) * 64 + n * 16 + o;
        P[((long)ch * 32 + kx) * 17 + ky] = make_float2(accr2, acci2);
    }
}

// ---------------------------------------------------------------------------
// F2 = K4+K5 fused, one (b,ho) plane per block.
//  K4: zsh[h][ky] = sum_kx P[plane][kx][ky] e^{+2pi i kx h/256}   (thread=h)
//  K5: out[plane*256+h][w] from zsh (2 rows per wave per iter, verified loop)
// ---------------------------------------------------------------------------
__global__ __launch_bounds__(256) void f2_inv(const float2* __restrict__ P,
                                              const float* __restrict__ bias,
                                              float* __restrict__ out) {
    __shared__ float2 psh[544];
    __shared__ float2 zsh[4352];  // [h*17+ky]
    int t = threadIdx.x;
    int plane = blockIdx.x;  // 0..511 = b*64 + ho
    long base = (long)plane * 544;
    psh[t] = P[base + t];
    psh[t + 256] = P[base + t + 256];
    if (t < 32) psh[t + 512] = P[base + t + 512];
    __syncthreads();

    // K4 phase (verified): thread t = h
    {
        float chh, shh;
        sincospif((float)t * (1.0f / 128.0f), &shh, &chh);  // step e^{+2pi i h/256}
        float pc = 1.f, psn = 0.f;
        float ar[17], ai[17];
#pragma unroll
        for (int ky = 0; ky < 17; ++ky) { ar[ky] = 0.f; ai[ky] = 0.f; }

        for (int kx = 0; kx < 32; ++kx) {
#pragma unroll
            for (int ky = 0; ky < 17; ++ky) {
                float2 v = psh[kx * 17 + ky];
                ar[ky] += v.x * pc - v.y * psn;
                ai[ky] += v.x * psn + v.y * pc;
            }
            float npc = pc * chh - psn * shh;
            psn = pc * shh + psn * chh;
            pc = npc;
        }
#pragma unroll
        for (int ky = 0; ky < 17; ++ky) zsh[t * 17 + ky] = make_float2(ar[ky], ai[ky]);
    }
    __syncthreads();

    // K5 phase (verified inner): 4 waves x 2 rows x 32 iters = 256 rows
    int wv = t >> 6;
    int lane = t & 63;
    float bv = bias[plane & 63];
    float c0, s0;
    sincospif((float)lane * (1.0f / 128.0f), &s0, &c0);  // step e^{+2pi i lane/256}
    const float inv = 1.0f / 65536.0f;
    const float inv2 = 2.0f / 65536.0f;
    long ob_plane = (long)plane * 65536;

    for (int it8 = 0; it8 < 32; ++it8) {
        int r0 = it8 * 8 + wv * 2;
        float pc = c0, psn = s0;  // phasor at ky=1
        float a00 = 0, a01 = 0, a02 = 0, a03 = 0;
        float a10 = 0, a11 = 0, a12 = 0, a13 = 0;

#pragma unroll
        for (int ky = 1; ky <= 16; ++ky) {
            float2 z0 = zsh[r0 * 17 + ky];
            float2 z1 = zsh[(r0 + 1) * 17 + ky];
            float A0 = z0.x * pc - z0.y * psn;
            float B0 = z0.x * psn + z0.y * pc;
            float A1 = z1.x * pc - z1.y * psn;
            float B1 = z1.x * psn + z1.y * pc;
            a00 += A0; a10 += A1;
            a01 += ((ky & 3) == 0) ? A0 : ((ky & 3) == 1) ? -B0 : ((ky & 3) == 2) ? -A0 : B0;
            a11 += ((ky & 3) == 0) ? A1 : ((ky & 3) == 1) ? -B1 : ((ky & 3) == 2) ? -A1 : B1;
            a02 += (ky & 1) ? -A0 : A0;
            a12 += (ky & 1) ? -A1 : A1;
            a03 += ((ky & 3) == 0) ? A0 : ((ky & 3) == 1) ? B0 : ((ky & 3) == 2) ? -A0 : -B0;
            a13 += ((ky & 3) == 0) ? A1 : ((ky & 3) == 1) ? B1 : ((ky & 3) == 2) ? -A1 : -B1;
            float npc = pc * c0 - psn * s0;
            psn = pc * s0 + psn * c0;
            pc = npc;
        }
        float base0 = zsh[r0 * 17].x * inv + bv;
        float base1 = zsh[(r0 + 1) * 17].x * inv + bv;
        long ob0 = ob_plane + (long)r0 * 256;
        long ob1 = ob0 + 256;
        out[ob0 + lane]       = fmaf(a00, inv2, base0);
        out[ob0 + 64 + lane]  = fmaf(a01, inv2, base0);
        out[ob0 + 128 + lane] = fmaf(a02, inv2, base0);
        out[ob0 + 192 + lane] = fmaf(a03, inv2, base0);
        out[ob1 + lane]       = fmaf(a10, inv2, base1);
        out[ob1 + 64 + lane]  = fmaf(a11, inv2, base1);
        out[ob1 + 128 + lane] = fmaf(a12, inv2, base1);
        out[ob1 + 192 + lane] = fmaf(a13, inv2, base1);
    }
}

extern "C" void kernel_launch(void* const* d_in, const int* in_sizes, int n_in,
                              void* d_out, int out_size, void* d_ws, size_t ws_size,
                              hipStream_t stream) {
    const float* x = (const float*)d_in[0];
    const float* wr = (const float*)d_in[1];
    const float* wi = (const float*)d_in[2];
    const float* bias = (const float*)d_in[3];
    float* out = (float*)d_out;
    float* ws = (float*)d_ws;

    float2* X2 = (float2*)(ws + 4456960);
    float2* P  = (float2*)(ws + 5014016);

    hipLaunchKernelGGL(f1_fw, dim3(512), dim3(256), 0, stream, x, X2);
    hipLaunchKernelGGL(k3_mix, dim3(512), dim3(256), 0, stream, X2, wr, wi, P);
    hipLaunchKernelGGL(f2_inv, dim3(512), dim3(256), 0, stream, P, bias, out);
}

// Round 8
// 121.125 us; speedup vs baseline: 1.5636x; 1.1948x over previous
//
#include <hip/hip_runtime.h>
#include <hip/hip_bf16.h>

// Problem constants
// B=8, C=64, H=256, W=256, NH=4, O=16 (HO=64), MX=32, MY=17
#define NROWS 131072
#define MY 17
#define MX 32

// ws layout (floats):
//   X2:   [4456960, +557056)  [(b*64+c)*32+kx][ky] float2
//   P:    [5014016, +557056)  [(b*64+ho)*32+kx][ky] float2

// ---------------------------------------------------------------------------
// F1 = K1+K2 fused, one (b,c) plane per block.
//  K1 (radix-4 along w + radix-2 along l):
//    X1[h][j] = sum_w x[h][w] e^{-2pi i j w/256}  -> LDS xs[h*17+j]
//    y(l) = (A + ca*B) + i*(cb*B),  A/B parity-selected planes
//    t(l) = y(l) + w8*y(l+32), w8 = e^{-pi i j/4}  (per-thread const)
//    X1 = sum_{l<32} t(l)*ph(l), ph step e^{-2pi i j/256}
//  K2 (radix-4 along h, in-place butterfly on xs):
//    stage1: xs[m] <- xs[m]+xs[m+128]; xs[m+128] <- xs[m]-xs[m+128]  (m<128)
//    then X2[kx][ky] = sum_{m<64} yk(m)*ph(m), ph step e^{-2pi i kx/256}
// ---------------------------------------------------------------------------
#define K1_ROWS 30
#define NCHUNK 9     // 8*30 + 16 = 256

__global__ __launch_bounds__(256) void f1_fw(const float* __restrict__ x,
                                             float2* __restrict__ X2) {
    __shared__ __align__(16) float s_lds[4][K1_ROWS][68];  // 32640 B
    __shared__ float2 xs[4352];                            // 34816 B  [h*17+ky]
    int t = threadIdx.x;
    int bc = blockIdx.x;  // 0..511
    const float* xp = x + (long)bc * 65536;

    // compute-phase constants
    int j = t % 17;
    int g = t / 17;      // 0..15 (g=15 only when t=255, inactive)
    int r0 = g * 2;
    int odd = j & 1;
    float ca = odd ? 0.f : ((j & 2) ? -1.f : 1.f);
    float cb = odd ? (((j & 3) == 1) ? -1.f : 1.f) : 0.f;
    float cj, sj;
    sincospif((float)j * (1.0f / 128.0f), &sj, &cj);
    sj = -sj;  // step e^{-2pi i j/256}
    float swv, cwv;
    sincospif((float)j * 0.25f, &swv, &cwv);
    swv = -swv;  // w8 = e^{-pi i j/4}
    float k1c = cwv * ca - swv * cb;
    float k2c = swv * ca + cwv * cb;
    const float4* A4 = (const float4*)&s_lds[odd ? 1 : 0][0][0] + r0 * 17;
    const float4* B4 = (const float4*)&s_lds[odd ? 3 : 2][0][0] + r0 * 17;

    float4 q0[2], q1[2], q2[2], q3[2];

#define F1_REGLOAD(cc)                                                         \
    {                                                                          \
        int nr_ = ((cc) < 8) ? K1_ROWS : 16;                                   \
        int items_ = nr_ * 16;                                                 \
        _Pragma("unroll")                                                      \
        for (int i = 0; i < 2; ++i) {                                          \
            int item = i * 256 + t;                                            \
            int it = item < items_ ? item : items_ - 1;                        \
            int r = it >> 4, cq = it & 15;                                     \
            const float4* xr =                                                 \
                (const float4*)(xp + ((cc) * K1_ROWS + r) * 256) + cq;         \
            q0[i] = xr[0];                                                     \
            q1[i] = xr[16];                                                    \
            q2[i] = xr[32];                                                    \
            q3[i] = xr[48];                                                    \
        }                                                                      \
    }

    F1_REGLOAD(0)

    for (int c = 0; c < NCHUNK; ++c) {
        int nr = (c < 8) ? K1_ROWS : 16;
        int items = nr * 16;

        // radix-4 combine (along w) + LDS write, from registers
#pragma unroll
        for (int i = 0; i < 2; ++i) {
            int item = i * 256 + t;
            if (item < items) {
                int r = item >> 4, cq = item & 15;
                float4 s02p, s02m, s13p, s13m;
                s02p.x = q0[i].x + q2[i].x; s02p.y = q0[i].y + q2[i].y;
                s02p.z = q0[i].z + q2[i].z; s02p.w = q0[i].w + q2[i].w;
                s02m.x = q0[i].x - q2[i].x; s02m.y = q0[i].y - q2[i].y;
                s02m.z = q0[i].z - q2[i].z; s02m.w = q0[i].w - q2[i].w;
                s13p.x = q1[i].x + q3[i].x; s13p.y = q1[i].y + q3[i].y;
                s13p.z = q1[i].z + q3[i].z; s13p.w = q1[i].w + q3[i].w;
                s13m.x = q1[i].x - q3[i].x; s13m.y = q1[i].y - q3[i].y;
                s13m.z = q1[i].z - q3[i].z; s13m.w = q1[i].w - q3[i].w;
                *(float4*)&s_lds[0][r][cq * 4] = s02p;
                *(float4*)&s_lds[1][r][cq * 4] = s02m;
                *(float4*)&s_lds[2][r][cq * 4] = s13p;
                *(float4*)&s_lds[3][r][cq * 4] = s13m;
            }
        }
        __syncthreads();

        // prefetch next chunk into registers (in flight during compute)
        if (c + 1 < NCHUNK) F1_REGLOAD(c + 1)

        // 17-mode DFT of this chunk (radix-2 over l: 32 steps)
        if (t < 255 && r0 + 2 <= nr) {
            float pc = 1.f, ps = 0.f;
            float ar0 = 0, ai0 = 0, ar1 = 0, ai1 = 0;

#define K1_STEP(a0e, b0e, a0f, b0f, a1e, b1e, a1f, b1f)               \
  { float t0re = fmaf(k1c, (b0f), fmaf(cwv, (a0f), fmaf(ca, (b0e), (a0e)))); \
    float t0im = fmaf(k2c, (b0f), fmaf(swv, (a0f), cb * (b0e)));      \
    float t1re = fmaf(k1c, (b1f), fmaf(cwv, (a1f), fmaf(ca, (b1e), (a1e)))); \
    float t1im = fmaf(k2c, (b1f), fmaf(swv, (a1f), cb * (b1e)));      \
    ar0 = fmaf(t0re, pc, ar0); ar0 = fmaf(-t0im, ps, ar0);            \
    ai0 = fmaf(t0re, ps, ai0); ai0 = fmaf(t0im, pc, ai0);             \
    ar1 = fmaf(t1re, pc, ar1); ar1 = fmaf(-t1im, ps, ar1);            \
    ai1 = fmaf(t1re, ps, ai1); ai1 = fmaf(t1im, pc, ai1);             \
    float nps = fmaf(pc, sj, ps * cj);                                \
    pc = fmaf(pc, cj, -(ps * sj)); ps = nps; }

#pragma unroll 2
            for (int l4 = 0; l4 < 8; ++l4) {
                float4 va0 = A4[l4], vb0 = B4[l4];
                float4 vA0 = A4[8 + l4], vB0 = B4[8 + l4];    // l+32
                float4 va1 = A4[17 + l4], vb1 = B4[17 + l4];
                float4 vA1 = A4[25 + l4], vB1 = B4[25 + l4];  // row+1, l+32
                K1_STEP(va0.x, vb0.x, vA0.x, vB0.x, va1.x, vb1.x, vA1.x, vB1.x)
                K1_STEP(va0.y, vb0.y, vA0.y, vB0.y, va1.y, vb1.y, vA1.y, vB1.y)
                K1_STEP(va0.z, vb0.z, vA0.z, vB0.z, va1.z, vb1.z, vA1.z, vB1.z)
                K1_STEP(va0.w, vb0.w, vA0.w, vB0.w, va1.w, vb1.w, vA1.w, vB1.w)
            }
#undef K1_STEP

            int h = c * K1_ROWS + r0;
            xs[h * 17 + j] = make_float2(ar0, ai0);
            xs[(h + 1) * 17 + j] = make_float2(ar1, ai1);
        }
        __syncthreads();
    }

    // K2: in-place radix-4 butterfly along h (stage 1: h vs h+128)
    for (int q = t; q < 2176; q += 256) {
        float2 a = xs[q], b = xs[q + 2176];
        xs[q] = make_float2(a.x + b.x, a.y + b.y);
        xs[q + 2176] = make_float2(a.x - b.x, a.y - b.y);
    }
    __syncthreads();
    // now: xs[0..1087]=u02p (m=0..63), xs[1088..2175]=u13p,
    //      xs[2176..3263]=u02m,        xs[3264..4351]=u13m   (each [m*17+ky])

    for (int q = t; q < 544; q += 256) {
        int kx = q / 17, ky = q % 17;
        int kodd = kx & 1;
        float cA = kodd ? 0.f : ((kx & 2) ? -1.f : 1.f);
        float cB = kodd ? (((kx & 3) == 1) ? -1.f : 1.f) : 0.f;
        float cBn = -cB;
        const float2* Aq = xs + (kodd ? 2176 : 0) + ky;
        float cs, ss;
        sincospif((float)kx * (1.0f / 128.0f), &ss, &cs);
        ss = -ss;  // step e^{-2pi i kx/256}
        float pc = 1.f, psn = 0.f;
        float ar = 0.f, ai = 0.f;
#pragma unroll 4
        for (int m = 0; m < 64; ++m) {
            float2 a = Aq[m * 17];
            float2 b = Aq[1088 + m * 17];
            float yre = fmaf(cBn, b.y, fmaf(cA, b.x, a.x));
            float yim = fmaf(cB, b.x, fmaf(cA, b.y, a.y));
            ar = fmaf(yre, pc, ar); ar = fmaf(-yim, psn, ar);
            ai = fmaf(yre, psn, ai); ai = fmaf(yim, pc, ai);
            float npc = pc * cs - psn * ss;
            psn = pc * ss + psn * cs;
            pc = npc;
        }
        X2[(long)bc * 544 + q] = make_float2(ar, ai);
    }
#undef F1_REGLOAD
}

// ---------------------------------------------------------------------------
// K3: P[b, n*16+o, kx, ky] = sum_i X2[b,i,kx,ky] * (wr + i wi)[n,i,o,kx,ky]
// grid 512: kx = bi&31, bh = (bi>>5)&3 (2 batches each), n = bi>>7 (verified)
// ---------------------------------------------------------------------------
__global__ __launch_bounds__(256) void k3_mix(const float2* __restrict__ X2,
                                              const float* __restrict__ wr_g,
                                              const float* __restrict__ wi_g,
                                              float2* __restrict__ P) {
    __shared__ float2 xsh[544];    // [ii][b][ky]
    __shared__ float2 wsh[4352];   // [ii][o][ky]
    int t = threadIdx.x;
    int bi = blockIdx.x;
    int kx = bi & 31;
    int bh = (bi >> 5) & 3;
    int n = bi >> 7;

    float accr0 = 0, acci0 = 0, accr1 = 0, acci1 = 0, accr2 = 0, acci2 = 0;

    for (int ic = 0; ic < 4; ++ic) {
        __syncthreads();
        for (int q = t; q < 544; q += 256) {
            int ii = q / 34;
            int rem = q % 34;
            int b = rem / 17;
            int ky = rem % 17;
            int i = ic * 16 + ii;
            xsh[q] = X2[((long)((bh * 2 + b) * 64 + i) * 32 + kx) * 17 + ky];
        }
        for (int q = t; q < 4352; q += 256) {
            int ii = q / 272;
            int rem = q % 272;
            int o = rem / 17;
            int ky = rem % 17;
            int i = ic * 16 + ii;
            long widx = ((long)((n * 64 + i) * 16 + o)) * 544 + kx * 17 + ky;
            wsh[q] = make_float2(wr_g[widx], wi_g[widx]);
        }
        __syncthreads();

#pragma unroll 3
        for (int rep = 0; rep < 3; ++rep) {
            int q = t + rep * 256;
            if (q < 544) {
                int ky = q % 17;
                int o = (q / 17) & 15;
                int b = q / 272;
                float ar = 0.f, ai = 0.f;
#pragma unroll
                for (int ii = 0; ii < 16; ++ii) {
                    float2 xv = xsh[ii * 34 + b * 17 + ky];
                    float2 wv = wsh[ii * 272 + o * 17 + ky];
                    ar += xv.x * wv.x - xv.y * wv.y;
                    ai += xv.x * wv.y + xv.y * wv.x;
                }
                if (rep == 0) { accr0 += ar; acci0 += ai; }
                else if (rep == 1) { accr1 += ar; acci1 += ai; }
                else { accr2 += ar; acci2 += ai; }
            }
        }
    }

    {
        int q = t;
        int ky = q % 17, o = (q / 17) & 15, b = q / 272;
        int ch = (bh * 2 + b) * 64 + n * 16 + o;
        P[((long)ch * 32 + kx) * 17 + ky] = make_float2(accr0, acci0);
    }
    {
        int q = t + 256;
        int ky = q % 17, o = (q / 17) & 15, b = q / 272;
        int ch = (bh * 2 + b) * 64 + n * 16 + o;
        P[((long)ch * 32 + kx) * 17 + ky] = make_float2(accr1, acci1);
    }
    if (t < 32) {
        int q = t + 512;
        int ky = q % 17, o = (q / 17) & 15, b = q / 272;
        int ch = (bh * 2 + b) * 64 + n * 16 + o;
        P[((long)ch * 32 + kx) * 17 + ky] = make_float2(accr2, acci2);
    }
}

// ---------------------------------------------------------------------------
// F2 = K4+K5 fused, one (b,ho) plane per block (verified R6 version).
// ---------------------------------------------------------------------------
__global__ __launch_bounds__(256) void f2_inv(const float2* __restrict__ P,
                                              const float* __restrict__ bias,
                                              float* __restrict__ out) {
    __shared__ float2 psh[544];
    __shared__ float2 zsh[4352];  // [h*17+ky]
    int t = threadIdx.x;
    int plane = blockIdx.x;  // 0..511 = b*64 + ho
    long base = (long)plane * 544;
    psh[t] = P[base + t];
    psh[t + 256] = P[base + t + 256];
    if (t < 32) psh[t + 512] = P[base + t + 512];
    __syncthreads();

    // K4 phase: thread t = h
    {
        float chh, shh;
        sincospif((float)t * (1.0f / 128.0f), &shh, &chh);
        float pc = 1.f, psn = 0.f;
        float ar[17], ai[17];
#pragma unroll
        for (int ky = 0; ky < 17; ++ky) { ar[ky] = 0.f; ai[ky] = 0.f; }

        for (int kx = 0; kx < 32; ++kx) {
#pragma unroll
            for (int ky = 0; ky < 17; ++ky) {
                float2 v = psh[kx * 17 + ky];
                ar[ky] += v.x * pc - v.y * psn;
                ai[ky] += v.x * psn + v.y * pc;
            }
            float npc = pc * chh - psn * shh;
            psn = pc * shh + psn * chh;
            pc = npc;
        }
#pragma unroll
        for (int ky = 0; ky < 17; ++ky) zsh[t * 17 + ky] = make_float2(ar[ky], ai[ky]);
    }
    __syncthreads();

    // K5 phase: 4 waves x 2 rows x 32 iters
    int wv = t >> 6;
    int lane = t & 63;
    float bv = bias[plane & 63];
    float c0, s0;
    sincospif((float)lane * (1.0f / 128.0f), &s0, &c0);
    const float inv = 1.0f / 65536.0f;
    const float inv2 = 2.0f / 65536.0f;
    long ob_plane = (long)plane * 65536;

    for (int it8 = 0; it8 < 32; ++it8) {
        int r0 = it8 * 8 + wv * 2;
        float pc = c0, psn = s0;
        float a00 = 0, a01 = 0, a02 = 0, a03 = 0;
        float a10 = 0, a11 = 0, a12 = 0, a13 = 0;

#pragma unroll
        for (int ky = 1; ky <= 16; ++ky) {
            float2 z0 = zsh[r0 * 17 + ky];
            float2 z1 = zsh[(r0 + 1) * 17 + ky];
            float A0 = z0.x * pc - z0.y * psn;
            float B0 = z0.x * psn + z0.y * pc;
            float A1 = z1.x * pc - z1.y * psn;
            float B1 = z1.x * psn + z1.y * pc;
            a00 += A0; a10 += A1;
            a01 += ((ky & 3) == 0) ? A0 : ((ky & 3) == 1) ? -B0 : ((ky & 3) == 2) ? -A0 : B0;
            a11 += ((ky & 3) == 0) ? A1 : ((ky & 3) == 1) ? -B1 : ((ky & 3) == 2) ? -A1 : B1;
            a02 += (ky & 1) ? -A0 : A0;
            a12 += (ky & 1) ? -A1 : A1;
            a03 += ((ky & 3) == 0) ? A0 : ((ky & 3) == 1) ? B0 : ((ky & 3) == 2) ? -A0 : -B0;
            a13 += ((ky & 3) == 0) ? A1 : ((ky & 3) == 1) ? B1 : ((ky & 3) == 2) ? -A1 : -B1;
            float npc = pc * c0 - psn * s0;
            psn = pc * s0 + psn * c0;
            pc = npc;
        }
        float base0 = zsh[r0 * 17].x * inv + bv;
        float base1 = zsh[(r0 + 1) * 17].x * inv + bv;
        long ob0 = ob_plane + (long)r0 * 256;
        long ob1 = ob0 + 256;
        out[ob0 + lane]       = fmaf(a00, inv2, base0);
        out[ob0 + 64 + lane]  = fmaf(a01, inv2, base0);
        out[ob0 + 128 + lane] = fmaf(a02, inv2, base0);
        out[ob0 + 192 + lane] = fmaf(a03, inv2, base0);
        out[ob1 + lane]       = fmaf(a10, inv2, base1);
        out[ob1 + 64 + lane]  = fmaf(a11, inv2, base1);
        out[ob1 + 128 + lane] = fmaf(a12, inv2, base1);
        out[ob1 + 192 + lane] = fmaf(a13, inv2, base1);
    }
}

extern "C" void kernel_launch(void* const* d_in, const int* in_sizes, int n_in,
                              void* d_out, int out_size, void* d_ws, size_t ws_size,
                              hipStream_t stream) {
    const float* x = (const float*)d_in[0];
    const float* wr = (const float*)d_in[1];
    const float* wi = (const float*)d_in[2];
    const float* bias = (const float*)d_in[3];
    float* out = (float*)d_out;
    float* ws = (float*)d_ws;

    float2* X2 = (float2*)(ws + 4456960);
    float2* P  = (float2*)(ws + 5014016);

    hipLaunchKernelGGL(f1_fw, dim3(512), dim3(256), 0, stream, x, X2);
    hipLaunchKernelGGL(k3_mix, dim3(512), dim3(256), 0, stream, X2, wr, wi, P);
    hipLaunchKernelGGL(f2_inv, dim3(512), dim3(256), 0, stream, P, bias, out);
}

// Round 9
// 120.616 us; speedup vs baseline: 1.5702x; 1.0042x over previous
//
#include <hip/hip_runtime.h>
#include <hip/hip_bf16.h>

// Problem constants
// B=8, C=64, H=256, W=256, NH=4, O=16 (HO=64), MX=32, MY=17
#define NROWS 131072
#define MY 17
#define MX 32

// ws layout (floats):
//   X2:   [4456960, +557056)  [(b*64+c)*32+kx][ky] float2
//   P:    [5014016, +557056)  [(b*64+ho)*32+kx][ky] float2

// ---------------------------------------------------------------------------
// F1 = K1+K2 fused, one (b,c) plane per block, 512 threads.
//  K1 (radix-4 along w + radix-2 along l): 1 row/thread, j=t%17, r=t/17
//  K2 (radix-4 along h, in-place butterfly on xs)
// ---------------------------------------------------------------------------
#define K1_ROWS 30
#define NCHUNK 9     // 8*30 + 16 = 256

__global__ __launch_bounds__(512) void f1_fw(const float* __restrict__ x,
                                             float2* __restrict__ X2) {
    __shared__ __align__(16) float s_lds[4][K1_ROWS][68];  // 32640 B
    __shared__ float2 xs[4352];                            // 34816 B  [h*17+ky]
    int t = threadIdx.x;
    int bc = blockIdx.x;  // 0..511
    const float* xp = x + (long)bc * 65536;

    // compute-phase constants: thread t<510: j = t%17, row r = t/17 (0..29)
    int j = t % 17;
    int r = t / 17;
    int rc = r < K1_ROWS ? r : 0;  // clamp for pointer init only
    int odd = j & 1;
    float ca = odd ? 0.f : ((j & 2) ? -1.f : 1.f);
    float cb = odd ? (((j & 3) == 1) ? -1.f : 1.f) : 0.f;
    float cj, sj;
    sincospif((float)j * (1.0f / 128.0f), &sj, &cj);
    sj = -sj;  // step e^{-2pi i j/256}
    float swv, cwv;
    sincospif((float)j * 0.25f, &swv, &cwv);
    swv = -swv;  // w8 = e^{-pi i j/4}
    float k1c = cwv * ca - swv * cb;
    float k2c = swv * ca + cwv * cb;
    const float4* A4 = (const float4*)&s_lds[odd ? 1 : 0][rc][0];
    const float4* B4 = (const float4*)&s_lds[odd ? 3 : 2][rc][0];

    float4 q0, q1, q2, q3;

#define F1_REGLOAD(cc)                                                         \
    {                                                                          \
        int nr_ = ((cc) < 8) ? K1_ROWS : 16;                                   \
        int items_ = nr_ * 16;                                                 \
        int it = t < items_ ? t : items_ - 1;                                  \
        int rr = it >> 4, cq = it & 15;                                        \
        const float4* xr =                                                     \
            (const float4*)(xp + ((cc) * K1_ROWS + rr) * 256) + cq;            \
        q0 = xr[0];                                                            \
        q1 = xr[16];                                                           \
        q2 = xr[32];                                                           \
        q3 = xr[48];                                                           \
    }

    F1_REGLOAD(0)

    for (int c = 0; c < NCHUNK; ++c) {
        int nr = (c < 8) ? K1_ROWS : 16;
        int items = nr * 16;

        // radix-4 combine (along w) + LDS write, from registers
        if (t < items) {
            int rr = t >> 4, cq = t & 15;
            float4 s02p, s02m, s13p, s13m;
            s02p.x = q0.x + q2.x; s02p.y = q0.y + q2.y;
            s02p.z = q0.z + q2.z; s02p.w = q0.w + q2.w;
            s02m.x = q0.x - q2.x; s02m.y = q0.y - q2.y;
            s02m.z = q0.z - q2.z; s02m.w = q0.w - q2.w;
            s13p.x = q1.x + q3.x; s13p.y = q1.y + q3.y;
            s13p.z = q1.z + q3.z; s13p.w = q1.w + q3.w;
            s13m.x = q1.x - q3.x; s13m.y = q1.y - q3.y;
            s13m.z = q1.z - q3.z; s13m.w = q1.w - q3.w;
            *(float4*)&s_lds[0][rr][cq * 4] = s02p;
            *(float4*)&s_lds[1][rr][cq * 4] = s02m;
            *(float4*)&s_lds[2][rr][cq * 4] = s13p;
            *(float4*)&s_lds[3][rr][cq * 4] = s13m;
        }
        __syncthreads();

        // prefetch next chunk into registers (in flight during compute)
        if (c + 1 < NCHUNK) F1_REGLOAD(c + 1)

        // 17-mode DFT of this chunk (radix-2 over l: 32 steps), 1 row/thread
        if (t < 510 && r < nr) {
            float pc = 1.f, ps = 0.f;
            float ar0 = 0, ai0 = 0;

#define K1_STEP(a0e, b0e, a0f, b0f)                                   \
  { float t0re = fmaf(k1c, (b0f), fmaf(cwv, (a0f), fmaf(ca, (b0e), (a0e)))); \
    float t0im = fmaf(k2c, (b0f), fmaf(swv, (a0f), cb * (b0e)));      \
    ar0 = fmaf(t0re, pc, ar0); ar0 = fmaf(-t0im, ps, ar0);            \
    ai0 = fmaf(t0re, ps, ai0); ai0 = fmaf(t0im, pc, ai0);             \
    float nps = fmaf(pc, sj, ps * cj);                                \
    pc = fmaf(pc, cj, -(ps * sj)); ps = nps; }

#pragma unroll 2
            for (int l4 = 0; l4 < 8; ++l4) {
                float4 va0 = A4[l4], vb0 = B4[l4];
                float4 vA0 = A4[8 + l4], vB0 = B4[8 + l4];  // l+32
                K1_STEP(va0.x, vb0.x, vA0.x, vB0.x)
                K1_STEP(va0.y, vb0.y, vA0.y, vB0.y)
                K1_STEP(va0.z, vb0.z, vA0.z, vB0.z)
                K1_STEP(va0.w, vb0.w, vA0.w, vB0.w)
            }
#undef K1_STEP

            int h = c * K1_ROWS + r;
            xs[h * 17 + j] = make_float2(ar0, ai0);
        }
        __syncthreads();
    }

    // K2: in-place radix-4 butterfly along h (stage 1: h vs h+128)
    for (int q = t; q < 2176; q += 512) {
        float2 a = xs[q], b = xs[q + 2176];
        xs[q] = make_float2(a.x + b.x, a.y + b.y);
        xs[q + 2176] = make_float2(a.x - b.x, a.y - b.y);
    }
    __syncthreads();
    // now: xs[0..1087]=u02p (m=0..63), xs[1088..2175]=u13p,
    //      xs[2176..3263]=u02m,        xs[3264..4351]=u13m   (each [m*17+ky])

    for (int q = t; q < 544; q += 512) {
        int kx = q / 17, ky = q % 17;
        int kodd = kx & 1;
        float cA = kodd ? 0.f : ((kx & 2) ? -1.f : 1.f);
        float cB = kodd ? (((kx & 3) == 1) ? -1.f : 1.f) : 0.f;
        float cBn = -cB;
        const float2* Aq = xs + (kodd ? 2176 : 0) + ky;
        float cs, ss;
        sincospif((float)kx * (1.0f / 128.0f), &ss, &cs);
        ss = -ss;  // step e^{-2pi i kx/256}
        float pc = 1.f, psn = 0.f;
        float ar = 0.f, ai = 0.f;
#pragma unroll 4
        for (int m = 0; m < 64; ++m) {
            float2 a = Aq[m * 17];
            float2 b = Aq[1088 + m * 17];
            float yre = fmaf(cBn, b.y, fmaf(cA, b.x, a.x));
            float yim = fmaf(cB, b.x, fmaf(cA, b.y, a.y));
            ar = fmaf(yre, pc, ar); ar = fmaf(-yim, psn, ar);
            ai = fmaf(yre, psn, ai); ai = fmaf(yim, pc, ai);
            float npc = pc * cs - psn * ss;
            psn = pc * ss + psn * cs;
            pc = npc;
        }
        X2[(long)bc * 544 + q] = make_float2(ar, ai);
    }
#undef F1_REGLOAD
}

// ---------------------------------------------------------------------------
// K3: P[b, n*16+o, kx, ky] = sum_i X2[b,i,kx,ky] * (wr + i wi)[n,i,o,kx,ky]
// grid 512: kx = bi&31, bh = (bi>>5)&3 (2 batches each), n = bi>>7 (verified)
// ---------------------------------------------------------------------------
__global__ __launch_bounds__(256) void k3_mix(const float2* __restrict__ X2,
                                              const float* __restrict__ wr_g,
                                              const float* __restrict__ wi_g,
                                              float2* __restrict__ P) {
    __shared__ float2 xsh[544];    // [ii][b][ky]
    __shared__ float2 wsh[4352];   // [ii][o][ky]
    int t = threadIdx.x;
    int bi = blockIdx.x;
    int kx = bi & 31;
    int bh = (bi >> 5) & 3;
    int n = bi >> 7;

    float accr0 = 0, acci0 = 0, accr1 = 0, acci1 = 0, accr2 = 0, acci2 = 0;

    for (int ic = 0; ic < 4; ++ic) {
        __syncthreads();
        for (int q = t; q < 544; q += 256) {
            int ii = q / 34;
            int rem = q % 34;
            int b = rem / 17;
            int ky = rem % 17;
            int i = ic * 16 + ii;
            xsh[q] = X2[((long)((bh * 2 + b) * 64 + i) * 32 + kx) * 17 + ky];
        }
        for (int q = t; q < 4352; q += 256) {
            int ii = q / 272;
            int rem = q % 272;
            int o = rem / 17;
            int ky = rem % 17;
            int i = ic * 16 + ii;
            long widx = ((long)((n * 64 + i) * 16 + o)) * 544 + kx * 17 + ky;
            wsh[q] = make_float2(wr_g[widx], wi_g[widx]);
        }
        __syncthreads();

#pragma unroll 3
        for (int rep = 0; rep < 3; ++rep) {
            int q = t + rep * 256;
            if (q < 544) {
                int ky = q % 17;
                int o = (q / 17) & 15;
                int b = q / 272;
                float ar = 0.f, ai = 0.f;
#pragma unroll
                for (int ii = 0; ii < 16; ++ii) {
                    float2 xv = xsh[ii * 34 + b * 17 + ky];
                    float2 wv = wsh[ii * 272 + o * 17 + ky];
                    ar += xv.x * wv.x - xv.y * wv.y;
                    ai += xv.x * wv.y + xv.y * wv.x;
                }
                if (rep == 0) { accr0 += ar; acci0 += ai; }
                else if (rep == 1) { accr1 += ar; acci1 += ai; }
                else { accr2 += ar; acci2 += ai; }
            }
        }
    }

    {
        int q = t;
        int ky = q % 17, o = (q / 17) & 15, b = q / 272;
        int ch = (bh * 2 + b) * 64 + n * 16 + o;
        P[((long)ch * 32 + kx) * 17 + ky] = make_float2(accr0, acci0);
    }
    {
        int q = t + 256;
        int ky = q % 17, o = (q / 17) & 15, b = q / 272;
        int ch = (bh * 2 + b) * 64 + n * 16 + o;
        P[((long)ch * 32 + kx) * 17 + ky] = make_float2(accr1, acci1);
    }
    if (t < 32) {
        int q = t + 512;
        int ky = q % 17, o = (q / 17) & 15, b = q / 272;
        int ch = (bh * 2 + b) * 64 + n * 16 + o;
        P[((long)ch * 32 + kx) * 17 + ky] = make_float2(accr2, acci2);
    }
}

// ---------------------------------------------------------------------------
// F2 = K4+K5 fused, one (b,ho) plane per block, 512 threads.
//  K4: h = t&255, ky-half by wave group (t>>8): waves 0-3 ky 0-8, waves 4-7 ky 9-16
//  K5: 8 waves x 2 rows x 16 iters (verified 2-row inner body)
// ---------------------------------------------------------------------------
__global__ __launch_bounds__(512) void f2_inv(const float2* __restrict__ P,
                                              const float* __restrict__ bias,
                                              float* __restrict__ out) {
    __shared__ float2 psh[544];
    __shared__ float2 zsh[4352];  // [h*17+ky]
    int t = threadIdx.x;
    int plane = blockIdx.x;  // 0..511 = b*64 + ho
    long base = (long)plane * 544;
    for (int q = t; q < 544; q += 512) psh[q] = P[base + q];
    __syncthreads();

    // K4 phase: h = t&255, half = t>>8 (wave-uniform)
    {
        int h = t & 255;
        int half = t >> 8;
        int kyb = half ? 9 : 0;
        int cnt = half ? 8 : 9;
        float chh, shh;
        sincospif((float)h * (1.0f / 128.0f), &shh, &chh);
        float pc = 1.f, psn = 0.f;
        float ar[9], ai[9];
#pragma unroll
        for (int u = 0; u < 9; ++u) { ar[u] = 0.f; ai[u] = 0.f; }

        const float2* pq = psh + kyb;
        for (int kx = 0; kx < 32; ++kx) {
#pragma unroll
            for (int u = 0; u < 9; ++u) {
                if (u < cnt) {
                    float2 v = pq[kx * 17 + u];
                    ar[u] += v.x * pc - v.y * psn;
                    ai[u] += v.x * psn + v.y * pc;
                }
            }
            float npc = pc * chh - psn * shh;
            psn = pc * shh + psn * chh;
            pc = npc;
        }
#pragma unroll
        for (int u = 0; u < 9; ++u)
            if (u < cnt) zsh[h * 17 + kyb + u] = make_float2(ar[u], ai[u]);
    }
    __syncthreads();

    // K5 phase: 8 waves x 2 rows x 16 iters
    int wv = t >> 6;      // 0..7
    int lane = t & 63;
    float bv = bias[plane & 63];
    float c0, s0;
    sincospif((float)lane * (1.0f / 128.0f), &s0, &c0);
    const float inv = 1.0f / 65536.0f;
    const float inv2 = 2.0f / 65536.0f;
    long ob_plane = (long)plane * 65536;

    for (int it16 = 0; it16 < 16; ++it16) {
        int r0 = it16 * 16 + wv * 2;
        float pc = c0, psn = s0;
        float a00 = 0, a01 = 0, a02 = 0, a03 = 0;
        float a10 = 0, a11 = 0, a12 = 0, a13 = 0;

#pragma unroll
        for (int ky = 1; ky <= 16; ++ky) {
            float2 z0 = zsh[r0 * 17 + ky];
            float2 z1 = zsh[(r0 + 1) * 17 + ky];
            float A0 = z0.x * pc - z0.y * psn;
            float B0 = z0.x * psn + z0.y * pc;
            float A1 = z1.x * pc - z1.y * psn;
            float B1 = z1.x * psn + z1.y * pc;
            a00 += A0; a10 += A1;
            a01 += ((ky & 3) == 0) ? A0 : ((ky & 3) == 1) ? -B0 : ((ky & 3) == 2) ? -A0 : B0;
            a11 += ((ky & 3) == 0) ? A1 : ((ky & 3) == 1) ? -B1 : ((ky & 3) == 2) ? -A1 : B1;
            a02 += (ky & 1) ? -A0 : A0;
            a12 += (ky & 1) ? -A1 : A1;
            a03 += ((ky & 3) == 0) ? A0 : ((ky & 3) == 1) ? B0 : ((ky & 3) == 2) ? -A0 : -B0;
            a13 += ((ky & 3) == 0) ? A1 : ((ky & 3) == 1) ? B1 : ((ky & 3) == 2) ? -A1 : -B1;
            float npc = pc * c0 - psn * s0;
            psn = pc * s0 + psn * c0;
            pc = npc;
        }
        float base0 = zsh[r0 * 17].x * inv + bv;
        float base1 = zsh[(r0 + 1) * 17].x * inv + bv;
        long ob0 = ob_plane + (long)r0 * 256;
        long ob1 = ob0 + 256;
        out[ob0 + lane]       = fmaf(a00, inv2, base0);
        out[ob0 + 64 + lane]  = fmaf(a01, inv2, base0);
        out[ob0 + 128 + lane] = fmaf(a02, inv2, base0);
        out[ob0 + 192 + lane] = fmaf(a03, inv2, base0);
        out[ob1 + lane]       = fmaf(a10, inv2, base1);
        out[ob1 + 64 + lane]  = fmaf(a11, inv2, base1);
        out[ob1 + 128 + lane] = fmaf(a12, inv2, base1);
        out[ob1 + 192 + lane] = fmaf(a13, inv2, base1);
    }
}

extern "C" void kernel_launch(void* const* d_in, const int* in_sizes, int n_in,
                              void* d_out, int out_size, void* d_ws, size_t ws_size,
                              hipStream_t stream) {
    const float* x = (const float*)d_in[0];
    const float* wr = (const float*)d_in[1];
    const float* wi = (const float*)d_in[2];
    const float* bias = (const float*)d_in[3];
    float* out = (float*)d_out;
    float* ws = (float*)d_ws;

    float2* X2 = (float2*)(ws + 4456960);
    float2* P  = (float2*)(ws + 5014016);

    hipLaunchKernelGGL(f1_fw, dim3(512), dim3(512), 0, stream, x, X2);
    hipLaunchKernelGGL(k3_mix, dim3(512), dim3(256), 0, stream, X2, wr, wi, P);
    hipLaunchKernelGGL(f2_inv, dim3(512), dim3(512), 0, stream, P, bias, out);
}